// Round 4
// baseline (847.519 us; speedup 1.0000x reference)
//
#include <hip/hip_runtime.h>
#include <cstdint>

#define N_NODES 50000
#define N_EDGES 800000

__device__ __forceinline__ float lrelu(float x) { return x >= 0.f ? x : 0.2f * x; }

__device__ __forceinline__ void onup(float& m, float& s, float e) {
  float nm = fmaxf(m, e);
  s = s * __expf(m - nm) + __expf(e - nm);
  m = nm;
}

// select v[h] without runtime register indexing (avoids scratch spill)
__device__ __forceinline__ float sel4(float v0, float v1, float v2, float v3, int h) {
  float r = v0;
  r = (h == 1) ? v1 : r;
  r = (h == 2) ? v2 : r;
  r = (h == 3) ? v3 : r;
  return r;
}

// ---------------- CSR build (pos+neg merged per kernel) ----------------

__global__ __launch_bounds__(256) void k_hist2(const int* __restrict__ ep, const int* __restrict__ en,
                                               int* __restrict__ cntP, int* __restrict__ cntN, int E, int half) {
  int b = blockIdx.x;
  const int* ei = (b < half) ? ep : en;
  int* cnt = (b < half) ? cntP : cntN;
  int e = (b % half) * 256 + threadIdx.x;
  if (e < E) atomicAdd(&cnt[ei[E + e]], 1);
}

__global__ __launch_bounds__(256) void k_scan_partial2(const int* __restrict__ cntP, const int* __restrict__ cntN,
                                                       int* __restrict__ partP, int* __restrict__ partN,
                                                       int N, int half) {
  int b = blockIdx.x;
  const int* cnt = (b < half) ? cntP : cntN;
  int* partial = (b < half) ? partP : partN;
  int bb = b % half;
  int t = threadIdx.x;
  int sum = 0;
#pragma unroll
  for (int i = 0; i < 4; i++) {
    int idx = bb * 1024 + i * 256 + t;
    if (idx < N) sum += cnt[idx];
  }
#pragma unroll
  for (int o = 32; o; o >>= 1) sum += __shfl_xor(sum, o);
  __shared__ int sh[4];
  if ((t & 63) == 0) sh[t >> 6] = sum;
  __syncthreads();
  if (t == 0) partial[bb] = sh[0] + sh[1] + sh[2] + sh[3];
}

__global__ __launch_bounds__(64) void k_scan_top2(const int* __restrict__ partP, const int* __restrict__ partN,
                                                  int* __restrict__ prefP, int* __restrict__ prefN,
                                                  int nb, int* __restrict__ offPN, int* __restrict__ offNN, int total) {
  const int* partial = (blockIdx.x == 0) ? partP : partN;
  int* pref = (blockIdx.x == 0) ? prefP : prefN;
  int* offN = (blockIdx.x == 0) ? offPN : offNN;
  int l = threadIdx.x;
  int v = (l < nb) ? partial[l] : 0;
  int x = v;
#pragma unroll
  for (int o = 1; o < 64; o <<= 1) {
    int y = __shfl_up(x, o);
    if (l >= o) x += y;
  }
  if (l < nb) pref[l] = x - v;  // exclusive
  if (l == 0) *offN = total;
}

__global__ __launch_bounds__(256) void k_scan_final2(const int* __restrict__ cntP, const int* __restrict__ cntN,
                                                     const int* __restrict__ prefP, const int* __restrict__ prefN,
                                                     int* __restrict__ offP, int* __restrict__ offN,
                                                     int N, int half) {
  int b = blockIdx.x;
  const int* cnt = (b < half) ? cntP : cntN;
  const int* pref = (b < half) ? prefP : prefN;
  int* off = (b < half) ? offP : offN;
  int bb = b % half;
  int t = threadIdx.x;
  int idx0 = bb * 1024 + t * 4;
  int v0 = (idx0 + 0 < N) ? cnt[idx0 + 0] : 0;
  int v1 = (idx0 + 1 < N) ? cnt[idx0 + 1] : 0;
  int v2 = (idx0 + 2 < N) ? cnt[idx0 + 2] : 0;
  int v3 = (idx0 + 3 < N) ? cnt[idx0 + 3] : 0;
  int s = v0 + v1 + v2 + v3;
  int lane = t & 63, w = t >> 6;
  int x = s;
#pragma unroll
  for (int o = 1; o < 64; o <<= 1) {
    int y = __shfl_up(x, o);
    if (lane >= o) x += y;
  }
  __shared__ int wtot[4];
  if (lane == 63) wtot[w] = x;
  __syncthreads();
  int woff = 0;
#pragma unroll
  for (int i = 0; i < 4; i++)
    if (i < w) woff += wtot[i];
  int excl = pref[bb] + woff + (x - s);
  if (idx0 + 0 < N) off[idx0 + 0] = excl;
  excl += v0;
  if (idx0 + 1 < N) off[idx0 + 1] = excl;
  excl += v1;
  if (idx0 + 2 < N) off[idx0 + 2] = excl;
  excl += v2;
  if (idx0 + 3 < N) off[idx0 + 3] = excl;
}

// scatter also records dst per sorted position (needed by edge-parallel alpha)
__global__ __launch_bounds__(256) void k_scatter2(const int* __restrict__ ep, const int* __restrict__ en,
                                                  const int* __restrict__ offP, const int* __restrict__ offN,
                                                  int* __restrict__ cntP, int* __restrict__ cntN,
                                                  int* __restrict__ srtP, int* __restrict__ srtN,
                                                  int* __restrict__ dstP, int* __restrict__ dstN,
                                                  int E, int half) {
  int b = blockIdx.x;
  const int* ei = (b < half) ? ep : en;
  const int* off = (b < half) ? offP : offN;
  int* cnt = (b < half) ? cntP : cntN;
  int* srt = (b < half) ? srtP : srtN;
  int* dstA = (b < half) ? dstP : dstN;
  int e = (b % half) * 256 + threadIdx.x;
  if (e < E) {
    int s = ei[e], d = ei[E + e];
    int p = atomicSub(&cnt[d], 1) - 1;  // reuses histogram, ends at zero
    int pos = off[d] + p;
    srt[pos] = s;
    dstA[pos] = d;
  }
}

// ---------------- fp32 GEMM: C[N x 2*Mhalf] = A[N x K] @ [B0 | B1] ----------------
// tile 128x64, 256 threads, 8x4 microtile, BK=32, b128 LDS reads.
// Epilogue: attention dots (one 64-ch head per blockIdx.y).

__global__ __launch_bounds__(256) void k_gemm(const float* __restrict__ A, const float* __restrict__ B0,
                                              const float* __restrict__ B1, float* __restrict__ C,
                                              int Nrows, int K, int Mhalf,
                                              const float* __restrict__ attSP, const float* __restrict__ attDP,
                                              const float* __restrict__ attSN, const float* __restrict__ attDN,
                                              float* __restrict__ oSP, float* __restrict__ oDP,
                                              float* __restrict__ oSN, float* __restrict__ oDN) {
  __shared__ float As[32][132];  // row stride 528 B (16B-aligned)
  __shared__ float Bs[32][64];
  int row0 = blockIdx.x * 128;
  int n0g = blockIdx.y * 64;
  const float* B = (n0g < Mhalf) ? B0 : B1;
  int n0 = n0g % Mhalf;
  int t = threadIdx.x;
  int tx = t & 15, ty = t >> 4;
  float acc[8][4];
#pragma unroll
  for (int i = 0; i < 8; i++)
#pragma unroll
    for (int j = 0; j < 4; j++) acc[i][j] = 0.f;
  int M = 2 * Mhalf;
  for (int k0 = 0; k0 < K; k0 += 32) {
#pragma unroll
    for (int i = 0; i < 4; i++) {
      int idx = t + i * 256;  // 0..1023
      int mrow = idx >> 3;
      int kg = idx & 7;
      int row = row0 + mrow;
      float4 av = make_float4(0.f, 0.f, 0.f, 0.f);
      if (row < Nrows) av = *(const float4*)&A[(size_t)row * K + k0 + kg * 4];
      As[kg * 4 + 0][mrow] = av.x;
      As[kg * 4 + 1][mrow] = av.y;
      As[kg * 4 + 2][mrow] = av.z;
      As[kg * 4 + 3][mrow] = av.w;
    }
#pragma unroll
    for (int i = 0; i < 2; i++) {
      int idx = t + i * 256;  // 0..511
      int kk = idx >> 4;
      int n4 = idx & 15;
      float4 bv = *(const float4*)&B[(size_t)(k0 + kk) * Mhalf + n0 + n4 * 4];
      *(float4*)&Bs[kk][n4 * 4] = bv;
    }
    __syncthreads();
#pragma unroll
    for (int k = 0; k < 32; k++) {
      float4 a0 = *(const float4*)&As[k][ty * 8];
      float4 a1 = *(const float4*)&As[k][ty * 8 + 4];
      float4 b4 = *(const float4*)&Bs[k][tx * 4];
      float a[8] = {a0.x, a0.y, a0.z, a0.w, a1.x, a1.y, a1.z, a1.w};
      float bb[4] = {b4.x, b4.y, b4.z, b4.w};
#pragma unroll
      for (int i = 0; i < 8; i++)
#pragma unroll
        for (int j = 0; j < 4; j++) acc[i][j] = fmaf(a[i], bb[j], acc[i][j]);
    }
    __syncthreads();
  }
#pragma unroll
  for (int i = 0; i < 8; i++) {
    int row = row0 + ty * 8 + i;
    if (row < Nrows) *(float4*)&C[(size_t)row * M + n0g + tx * 4] = *(float4*)&acc[i][0];
  }
  // ---- fused attention dots ----
  int isNeg = (n0g >= Mhalf) ? 1 : 0;
  int head = (n0g - (isNeg ? Mhalf : 0)) >> 6;
  int H = Mhalf >> 6;
  const float* wS = (isNeg ? attSN : attSP) + head * 64;
  const float* wD = (isNeg ? attDN : attDP) + head * 64;
  float* oS = isNeg ? oSN : oSP;
  float* oD = isNeg ? oDN : oDP;
  float4 wsv = *(const float4*)&wS[tx * 4];
  float4 wdv = *(const float4*)&wD[tx * 4];
#pragma unroll
  for (int i = 0; i < 8; i++) {
    float ps = acc[i][0] * wsv.x + acc[i][1] * wsv.y + acc[i][2] * wsv.z + acc[i][3] * wsv.w;
    float pd = acc[i][0] * wdv.x + acc[i][1] * wdv.y + acc[i][2] * wdv.z + acc[i][3] * wdv.w;
#pragma unroll
    for (int o = 1; o < 16; o <<= 1) {
      ps += __shfl_xor(ps, o);
      pd += __shfl_xor(pd, o);
    }
    int row = row0 + ty * 8 + i;
    if (tx == 0 && row < Nrows) {
      oS[(size_t)row * H + head] = ps;
      oD[(size_t)row * H + head] = pd;
    }
  }
}

// ---------------- softmax stats (layer 0: 4 heads) ----------------

struct MS4 { float m0, m1, m2, m3, s0, s1, s2, s3; };

__device__ __forceinline__ MS4 stats_heads(const float* __restrict__ as, float4 sl, float4 ad,
                                           const int* __restrict__ srt, int base, int deg, int l) {
  MS4 r;
  r.m0 = r.m1 = r.m2 = r.m3 = -1e30f;
  r.s0 = r.s1 = r.s2 = r.s3 = 0.f;
  if (l == 0) {  // self edge seeds lane 0
    r.m0 = lrelu(sl.x + ad.x); r.s0 = 1.f;
    r.m1 = lrelu(sl.y + ad.y); r.s1 = 1.f;
    r.m2 = lrelu(sl.z + ad.z); r.s2 = 1.f;
    r.m3 = lrelu(sl.w + ad.w); r.s3 = 1.f;
  }
  for (int i = l; i < deg; i += 64) {
    int s = srt[base + i];
    float4 av = *(const float4*)&as[(size_t)s * 4];
    onup(r.m0, r.s0, lrelu(av.x + ad.x));
    onup(r.m1, r.s1, lrelu(av.y + ad.y));
    onup(r.m2, r.s2, lrelu(av.z + ad.z));
    onup(r.m3, r.s3, lrelu(av.w + ad.w));
  }
#pragma unroll
  for (int o = 32; o; o >>= 1) {
    float mo, so, nm;
    mo = __shfl_xor(r.m0, o); so = __shfl_xor(r.s0, o);
    nm = fmaxf(r.m0, mo); r.s0 = r.s0 * __expf(r.m0 - nm) + so * __expf(mo - nm); r.m0 = nm;
    mo = __shfl_xor(r.m1, o); so = __shfl_xor(r.s1, o);
    nm = fmaxf(r.m1, mo); r.s1 = r.s1 * __expf(r.m1 - nm) + so * __expf(mo - nm); r.m1 = nm;
    mo = __shfl_xor(r.m2, o); so = __shfl_xor(r.s2, o);
    nm = fmaxf(r.m2, mo); r.s2 = r.s2 * __expf(r.m2 - nm) + so * __expf(mo - nm); r.m2 = nm;
    mo = __shfl_xor(r.m3, o); so = __shfl_xor(r.s3, o);
    nm = fmaxf(r.m3, mo); r.s3 = r.s3 * __expf(r.m3 - nm) + so * __expf(mo - nm); r.m3 = nm;
  }
  return r;
}

// per node (wave/node): write m[4], inv[4], selfAlpha[4] for both signs
__global__ __launch_bounds__(256) void k_stats0(const float* __restrict__ asP, const float* __restrict__ adP,
                                                const int* __restrict__ offP, const int* __restrict__ srtP,
                                                const float* __restrict__ asN, const float* __restrict__ adN,
                                                const int* __restrict__ offN, const int* __restrict__ srtN,
                                                float* __restrict__ mP, float* __restrict__ invP, float* __restrict__ slfP,
                                                float* __restrict__ mN, float* __restrict__ invN, float* __restrict__ slfN,
                                                int N) {
  int n = blockIdx.x * 4 + (threadIdx.x >> 6);
  if (n >= N) return;
  int l = threadIdx.x & 63;
  {
    int base = offP[n], deg = offP[n + 1] - base;
    float4 ad4 = *(const float4*)&adP[(size_t)n * 4];
    float4 as4 = *(const float4*)&asP[(size_t)n * 4];
    MS4 r = stats_heads(asP, as4, ad4, srtP, base, deg, l);
    if (l == 0) {
      float i0 = 1.f / (r.s0 + 1e-16f), i1 = 1.f / (r.s1 + 1e-16f);
      float i2 = 1.f / (r.s2 + 1e-16f), i3 = 1.f / (r.s3 + 1e-16f);
      *(float4*)&mP[(size_t)n * 4] = make_float4(r.m0, r.m1, r.m2, r.m3);
      *(float4*)&invP[(size_t)n * 4] = make_float4(i0, i1, i2, i3);
      *(float4*)&slfP[(size_t)n * 4] =
          make_float4(__expf(lrelu(as4.x + ad4.x) - r.m0) * i0, __expf(lrelu(as4.y + ad4.y) - r.m1) * i1,
                      __expf(lrelu(as4.z + ad4.z) - r.m2) * i2, __expf(lrelu(as4.w + ad4.w) - r.m3) * i3);
    }
  }
  {
    int base = offN[n], deg = offN[n + 1] - base;
    float4 ad4 = *(const float4*)&adN[(size_t)n * 4];
    float4 as4 = *(const float4*)&asN[(size_t)n * 4];
    MS4 r = stats_heads(asN, as4, ad4, srtN, base, deg, l);
    if (l == 0) {
      float i0 = 1.f / (r.s0 + 1e-16f), i1 = 1.f / (r.s1 + 1e-16f);
      float i2 = 1.f / (r.s2 + 1e-16f), i3 = 1.f / (r.s3 + 1e-16f);
      *(float4*)&mN[(size_t)n * 4] = make_float4(r.m0, r.m1, r.m2, r.m3);
      *(float4*)&invN[(size_t)n * 4] = make_float4(i0, i1, i2, i3);
      *(float4*)&slfN[(size_t)n * 4] =
          make_float4(__expf(lrelu(as4.x + ad4.x) - r.m0) * i0, __expf(lrelu(as4.y + ad4.y) - r.m1) * i1,
                      __expf(lrelu(as4.z + ad4.z) - r.m2) * i2, __expf(lrelu(as4.w + ad4.w) - r.m3) * i3);
    }
  }
}

// edge-parallel alpha finalize (layer 0, 4 heads), pos+neg merged
__global__ __launch_bounds__(256) void k_alpha0(const float* __restrict__ asP, const float* __restrict__ adP,
                                                const int* __restrict__ srtP, const int* __restrict__ dstP,
                                                const float* __restrict__ mP, const float* __restrict__ invP,
                                                float* __restrict__ alphaP,
                                                const float* __restrict__ asN, const float* __restrict__ adN,
                                                const int* __restrict__ srtN, const int* __restrict__ dstN,
                                                const float* __restrict__ mN, const float* __restrict__ invN,
                                                float* __restrict__ alphaN, int E, int half) {
  int b = blockIdx.x;
  const float* as = (b < half) ? asP : asN;
  const float* ad = (b < half) ? adP : adN;
  const int* srt = (b < half) ? srtP : srtN;
  const int* dstA = (b < half) ? dstP : dstN;
  const float* m = (b < half) ? mP : mN;
  const float* inv = (b < half) ? invP : invN;
  float* alpha = (b < half) ? alphaP : alphaN;
  int e = (b % half) * 256 + threadIdx.x;
  if (e >= E) return;
  int s = srt[e], d = dstA[e];
  float4 av = *(const float4*)&as[(size_t)s * 4];
  float4 dv = *(const float4*)&ad[(size_t)d * 4];
  float4 mv = *(const float4*)&m[(size_t)d * 4];
  float4 iv = *(const float4*)&inv[(size_t)d * 4];
  float4 r;
  r.x = __expf(lrelu(av.x + dv.x) - mv.x) * iv.x;
  r.y = __expf(lrelu(av.y + dv.y) - mv.y) * iv.y;
  r.z = __expf(lrelu(av.z + dv.z) - mv.z) * iv.z;
  r.w = __expf(lrelu(av.w + dv.w) - mv.w) * iv.w;
  *(float4*)&alpha[(size_t)e * 4] = r;
}

// ---------------- layer-0 gather: wave/node, pure weighted gather, 8-way MLP ----------------

__device__ __forceinline__ float4 gather0_half(const float4* __restrict__ h0v, int col4,
                                               const float* __restrict__ alpha, float wself, int n,
                                               const int* __restrict__ srt, int base, int deg, int l, int hl) {
  float4 acc;
  {
    float4 hv = h0v[(size_t)n * 128 + col4 + l];
    acc.x = wself * hv.x; acc.y = wself * hv.y; acc.z = wself * hv.z; acc.w = wself * hv.w;
  }
  for (int j = 0; j < deg; j += 8) {
    int idx[8];
    float w[8];
#pragma unroll
    for (int s2 = 0; s2 < 8; s2++) {
      int jj = j + s2;
      bool v = jj < deg;
      int p = base + (v ? jj : 0);
      idx[s2] = srt[p];
      w[s2] = v ? alpha[(size_t)p * 4 + hl] : 0.f;
    }
#pragma unroll
    for (int s2 = 0; s2 < 8; s2++) {
      float4 hv = h0v[(size_t)idx[s2] * 128 + col4 + l];
      acc.x = fmaf(w[s2], hv.x, acc.x);
      acc.y = fmaf(w[s2], hv.y, acc.y);
      acc.z = fmaf(w[s2], hv.z, acc.z);
      acc.w = fmaf(w[s2], hv.w, acc.w);
    }
  }
  return acc;
}

__global__ __launch_bounds__(256) void k_gather0(const float* __restrict__ h0,
                                                 const int* __restrict__ offP, const int* __restrict__ srtP,
                                                 const float* __restrict__ alphaP, const float* __restrict__ slfP,
                                                 const int* __restrict__ offN, const int* __restrict__ srtN,
                                                 const float* __restrict__ alphaN, const float* __restrict__ slfN,
                                                 const float* __restrict__ bP, const float* __restrict__ bN,
                                                 float* __restrict__ xbuf, int N) {
  int n = blockIdx.x * 4 + (threadIdx.x >> 6);
  if (n >= N) return;
  int l = threadIdx.x & 63;
  int hl = l >> 4;
  const float4* h0v = (const float4*)h0;

  int baseP = offP[n], degP = offP[n + 1] - baseP;
  float wsp = slfP[(size_t)n * 4 + hl];
  float4 accP = gather0_half(h0v, 0, alphaP, wsp, n, srtP, baseP, degP, l, hl);

  int baseN = offN[n], degN = offN[n + 1] - baseN;
  float wsn = slfN[(size_t)n * 4 + hl];
  float4 accN = gather0_half(h0v, 64, alphaN, wsn, n, srtN, baseN, degN, l, hl);

  float4 bp = *(const float4*)&bP[l * 4];
  float4 bn = *(const float4*)&bN[l * 4];
  float rx = accP.x + bp.x - accN.x - bn.x;
  float ry = accP.y + bp.y - accN.y - bn.y;
  float rz = accP.z + bp.z - accN.z - bn.z;
  float rw = accP.w + bp.w - accN.w - bn.w;
  float4 r;
  r.x = rx > 0.f ? rx : expm1f(rx);
  r.y = ry > 0.f ? ry : expm1f(ry);
  r.z = rz > 0.f ? rz : expm1f(rz);
  r.w = rw > 0.f ? rw : expm1f(rw);
  *(float4*)&xbuf[(size_t)n * 256 + l * 4] = r;
}

// ---------------- layer-1 stats / alpha / gather (1 head, 64 ch) ----------------

__device__ __forceinline__ void stats1(const float* __restrict__ as, float sl, float ad,
                                       const int* __restrict__ srt, int base, int deg, int l,
                                       float& m, float& s) {
  m = -1e30f;
  s = 0.f;
  if (l == 0) {
    m = lrelu(sl + ad);
    s = 1.f;
  }
  for (int i = l; i < deg; i += 64) onup(m, s, lrelu(as[srt[base + i]] + ad));
#pragma unroll
  for (int o = 32; o; o >>= 1) {
    float mo = __shfl_xor(m, o);
    float so = __shfl_xor(s, o);
    float nm = fmaxf(m, mo);
    s = s * __expf(m - nm) + so * __expf(mo - nm);
    m = nm;
  }
}

__global__ __launch_bounds__(256) void k_stats1(const float* __restrict__ asP, const float* __restrict__ adP,
                                                const int* __restrict__ offP, const int* __restrict__ srtP,
                                                const float* __restrict__ asN, const float* __restrict__ adN,
                                                const int* __restrict__ offN, const int* __restrict__ srtN,
                                                float* __restrict__ mP, float* __restrict__ invP, float* __restrict__ slfP,
                                                float* __restrict__ mN, float* __restrict__ invN, float* __restrict__ slfN,
                                                int N) {
  int n = blockIdx.x * 4 + (threadIdx.x >> 6);
  if (n >= N) return;
  int l = threadIdx.x & 63;
  {
    int base = offP[n], deg = offP[n + 1] - base;
    float ad = adP[n], as = asP[n];
    float m, s;
    stats1(asP, as, ad, srtP, base, deg, l, m, s);
    if (l == 0) {
      float iv = 1.f / (s + 1e-16f);
      mP[n] = m;
      invP[n] = iv;
      slfP[n] = __expf(lrelu(as + ad) - m) * iv;
    }
  }
  {
    int base = offN[n], deg = offN[n + 1] - base;
    float ad = adN[n], as = asN[n];
    float m, s;
    stats1(asN, as, ad, srtN, base, deg, l, m, s);
    if (l == 0) {
      float iv = 1.f / (s + 1e-16f);
      mN[n] = m;
      invN[n] = iv;
      slfN[n] = __expf(lrelu(as + ad) - m) * iv;
    }
  }
}

__global__ __launch_bounds__(256) void k_alpha1(const float* __restrict__ asP, const float* __restrict__ adP,
                                                const int* __restrict__ srtP, const int* __restrict__ dstP,
                                                const float* __restrict__ mP, const float* __restrict__ invP,
                                                float* __restrict__ alphaP,
                                                const float* __restrict__ asN, const float* __restrict__ adN,
                                                const int* __restrict__ srtN, const int* __restrict__ dstN,
                                                const float* __restrict__ mN, const float* __restrict__ invN,
                                                float* __restrict__ alphaN, int E, int half) {
  int b = blockIdx.x;
  const float* as = (b < half) ? asP : asN;
  const float* ad = (b < half) ? adP : adN;
  const int* srt = (b < half) ? srtP : srtN;
  const int* dstA = (b < half) ? dstP : dstN;
  const float* m = (b < half) ? mP : mN;
  const float* inv = (b < half) ? invP : invN;
  float* alpha = (b < half) ? alphaP : alphaN;
  int e = (b % half) * 256 + threadIdx.x;
  if (e >= E) return;
  int s = srt[e], d = dstA[e];
  alpha[e] = __expf(lrelu(as[s] + ad[d]) - m[d]) * inv[d];
}

__device__ __forceinline__ float gather1_half(const float* __restrict__ h1, int colOff,
                                              const float* __restrict__ alpha, float wself, int n,
                                              const int* __restrict__ srt, int base, int deg, int l) {
  float acc = wself * h1[(size_t)n * 128 + colOff + l];
  for (int j = 0; j < deg; j += 8) {
    int idx[8];
    float w[8];
#pragma unroll
    for (int s2 = 0; s2 < 8; s2++) {
      int jj = j + s2;
      bool v = jj < deg;
      int p = base + (v ? jj : 0);
      idx[s2] = srt[p];
      w[s2] = v ? alpha[p] : 0.f;
    }
#pragma unroll
    for (int s2 = 0; s2 < 8; s2++) acc = fmaf(w[s2], h1[(size_t)idx[s2] * 128 + colOff + l], acc);
  }
  return acc;
}

__global__ __launch_bounds__(256) void k_gather1(const float* __restrict__ h1,
                                                 const int* __restrict__ offP, const int* __restrict__ srtP,
                                                 const float* __restrict__ alphaP, const float* __restrict__ slfP,
                                                 const int* __restrict__ offN, const int* __restrict__ srtN,
                                                 const float* __restrict__ alphaN, const float* __restrict__ slfN,
                                                 const float* __restrict__ bP, const float* __restrict__ bN,
                                                 float* __restrict__ out, int N) {
  int n = blockIdx.x * 4 + (threadIdx.x >> 6);
  if (n >= N) return;
  int l = threadIdx.x & 63;
  int baseP = offP[n], degP = offP[n + 1] - baseP;
  float accP = gather1_half(h1, 0, alphaP, slfP[n], n, srtP, baseP, degP, l);
  int baseN = offN[n], degN = offN[n + 1] - baseN;
  float accN = gather1_half(h1, 64, alphaN, slfN[n], n, srtN, baseN, degN, l);
  out[(size_t)n * 64 + l] = (accP + bP[l]) - (accN + bN[l]);
}

// ---------------- launch ----------------

extern "C" void kernel_launch(void* const* d_in, const int* in_sizes, int n_in,
                              void* d_out, int out_size, void* d_ws, size_t ws_size,
                              hipStream_t stream) {
  const float* x = (const float*)d_in[0];
  const int* ep = (const int*)d_in[1];
  const int* en = (const int*)d_in[2];
  const float* W0p = (const float*)d_in[3];
  const float* asrc0p = (const float*)d_in[4];
  const float* adst0p = (const float*)d_in[5];
  const float* b0p = (const float*)d_in[6];
  const float* W0n = (const float*)d_in[7];
  const float* asrc0n = (const float*)d_in[8];
  const float* adst0n = (const float*)d_in[9];
  const float* b0n = (const float*)d_in[10];
  const float* W1p = (const float*)d_in[11];
  const float* asrc1p = (const float*)d_in[12];
  const float* adst1p = (const float*)d_in[13];
  const float* b1p = (const float*)d_in[14];
  const float* W1n = (const float*)d_in[15];
  const float* asrc1n = (const float*)d_in[16];
  const float* adst1n = (const float*)d_in[17];
  const float* b1n = (const float*)d_in[18];

  const int N = N_NODES, E = N_EDGES;
  char* base = (char*)d_ws;
  size_t o = 0;
  auto alloc = [&](size_t bytes) -> void* {
    void* r = base + o;
    o = (o + bytes + 255) & ~(size_t)255;
    return r;
  };
  int* cnt_p = (int*)alloc((size_t)N * 4);
  int* cnt_n = (int*)alloc((size_t)N * 4);
  size_t cntBytes = o;  // memset covers both count arrays (+padding)
  int* off_p = (int*)alloc((size_t)(N + 1) * 4);
  int* off_n = (int*)alloc((size_t)(N + 1) * 4);
  int* part_p = (int*)alloc(1024 * 4);
  int* part_n = (int*)alloc(1024 * 4);
  int* pref_p = (int*)alloc(1024 * 4);
  int* pref_n = (int*)alloc(1024 * 4);
  int* srt_p = (int*)alloc((size_t)E * 4);
  int* srt_n = (int*)alloc((size_t)E * 4);
  int* dst_p = (int*)alloc((size_t)E * 4);
  int* dst_n = (int*)alloc((size_t)E * 4);
  float* h0 = (float*)alloc((size_t)N * 512 * 4);
  float* as0p = (float*)alloc((size_t)N * 4 * 4);
  float* ad0p = (float*)alloc((size_t)N * 4 * 4);
  float* as0n = (float*)alloc((size_t)N * 4 * 4);
  float* ad0n = (float*)alloc((size_t)N * 4 * 4);
  float* as1p = (float*)alloc((size_t)N * 4);
  float* ad1p = (float*)alloc((size_t)N * 4);
  float* as1n = (float*)alloc((size_t)N * 4);
  float* ad1n = (float*)alloc((size_t)N * 4);
  float* m0p = (float*)alloc((size_t)N * 4 * 4);
  float* inv0p = (float*)alloc((size_t)N * 4 * 4);
  float* slf0p = (float*)alloc((size_t)N * 4 * 4);
  float* m0n = (float*)alloc((size_t)N * 4 * 4);
  float* inv0n = (float*)alloc((size_t)N * 4 * 4);
  float* slf0n = (float*)alloc((size_t)N * 4 * 4);
  float* m1p = (float*)alloc((size_t)N * 4);
  float* inv1p = (float*)alloc((size_t)N * 4);
  float* slf1p = (float*)alloc((size_t)N * 4);
  float* m1n = (float*)alloc((size_t)N * 4);
  float* inv1n = (float*)alloc((size_t)N * 4);
  float* slf1n = (float*)alloc((size_t)N * 4);
  float* alpha0p = (float*)alloc((size_t)E * 4 * 4);
  float* alpha0n = (float*)alloc((size_t)E * 4 * 4);
  float* alpha1p = (float*)alloc((size_t)E * 4);
  float* alpha1n = (float*)alloc((size_t)E * 4);
  float* xbuf = (float*)alloc((size_t)N * 256 * 4);
  float* h1 = h0;  // alias: h0 dead once layer-0 gather completes

  hipMemsetAsync(base, 0, cntBytes, stream);

  int egrid = (E + 255) / 256;
  int nb = (N + 1023) / 1024;  // 49
  k_hist2<<<2 * egrid, 256, 0, stream>>>(ep, en, cnt_p, cnt_n, E, egrid);
  k_scan_partial2<<<2 * nb, 256, 0, stream>>>(cnt_p, cnt_n, part_p, part_n, N, nb);
  k_scan_top2<<<2, 64, 0, stream>>>(part_p, part_n, pref_p, pref_n, nb, off_p + N, off_n + N, E);
  k_scan_final2<<<2 * nb, 256, 0, stream>>>(cnt_p, cnt_n, pref_p, pref_n, off_p, off_n, N, nb);
  k_scatter2<<<2 * egrid, 256, 0, stream>>>(ep, en, off_p, off_n, cnt_p, cnt_n, srt_p, srt_n, dst_p, dst_n, E, egrid);

  int ngrid = (N + 3) / 4;
  // layer 0
  dim3 g0((N + 127) / 128, 8);
  k_gemm<<<g0, 256, 0, stream>>>(x, W0p, W0n, h0, N, 128, 256,
                                 asrc0p, adst0p, asrc0n, adst0n, as0p, ad0p, as0n, ad0n);
  k_stats0<<<ngrid, 256, 0, stream>>>(as0p, ad0p, off_p, srt_p, as0n, ad0n, off_n, srt_n,
                                      m0p, inv0p, slf0p, m0n, inv0n, slf0n, N);
  k_alpha0<<<2 * egrid, 256, 0, stream>>>(as0p, ad0p, srt_p, dst_p, m0p, inv0p, alpha0p,
                                          as0n, ad0n, srt_n, dst_n, m0n, inv0n, alpha0n, E, egrid);
  k_gather0<<<ngrid, 256, 0, stream>>>(h0, off_p, srt_p, alpha0p, slf0p,
                                       off_n, srt_n, alpha0n, slf0n, b0p, b0n, xbuf, N);

  // layer 1
  dim3 g1((N + 127) / 128, 2);
  k_gemm<<<g1, 256, 0, stream>>>(xbuf, W1p, W1n, h1, N, 256, 64,
                                 asrc1p, adst1p, asrc1n, adst1n, as1p, ad1p, as1n, ad1n);
  k_stats1<<<ngrid, 256, 0, stream>>>(as1p, ad1p, off_p, srt_p, as1n, ad1n, off_n, srt_n,
                                      m1p, inv1p, slf1p, m1n, inv1n, slf1n, N);
  k_alpha1<<<2 * egrid, 256, 0, stream>>>(as1p, ad1p, srt_p, dst_p, m1p, inv1p, alpha1p,
                                          as1n, ad1n, srt_n, dst_n, m1n, inv1n, alpha1n, E, egrid);
  k_gather1<<<ngrid, 256, 0, stream>>>(h1, off_p, srt_p, alpha1p, slf1p,
                                       off_n, srt_n, alpha1n, slf1n, b1p, b1n, (float*)d_out, N);
}

// Round 6
// 637.806 us; speedup vs baseline: 1.3288x; 1.3288x over previous
//
#include <hip/hip_runtime.h>
#include <cstdint>

#define N_NODES 50000
#define N_EDGES 800000

typedef __attribute__((ext_vector_type(8))) short bf16x8;
typedef __attribute__((ext_vector_type(4))) float f32x4;

__device__ __forceinline__ float lrelu(float x) { return x >= 0.f ? x : 0.2f * x; }

__device__ __forceinline__ void onup(float& m, float& s, float e) {
  float nm = fmaxf(m, e);
  s = s * __expf(m - nm) + __expf(e - nm);
  m = nm;
}

__device__ __forceinline__ unsigned short f2b(float f) {  // fp32 -> bf16 RNE
  unsigned int u = __float_as_uint(f);
  u += 0x7FFFu + ((u >> 16) & 1u);
  return (unsigned short)(u >> 16);
}
__device__ __forceinline__ float blo(unsigned int u) { return __uint_as_float(u << 16); }
__device__ __forceinline__ float bhi(unsigned int u) { return __uint_as_float(u & 0xFFFF0000u); }

__device__ __forceinline__ float sel4(float v0, float v1, float v2, float v3, int h) {
  float r = v0;
  r = (h == 1) ? v1 : r;
  r = (h == 2) ? v2 : r;
  r = (h == 3) ? v3 : r;
  return r;
}

// ---------------- CSR build (pos+neg merged per kernel) ----------------

__global__ __launch_bounds__(256) void k_hist2(const int* __restrict__ ep, const int* __restrict__ en,
                                               int* __restrict__ cntP, int* __restrict__ cntN, int E, int half) {
  int b = blockIdx.x;
  const int* ei = (b < half) ? ep : en;
  int* cnt = (b < half) ? cntP : cntN;
  int e = (b % half) * 256 + threadIdx.x;
  if (e < E) atomicAdd(&cnt[ei[E + e]], 1);
}

__global__ __launch_bounds__(256) void k_scan_partial2(const int* __restrict__ cntP, const int* __restrict__ cntN,
                                                       int* __restrict__ partP, int* __restrict__ partN,
                                                       int N, int half) {
  int b = blockIdx.x;
  const int* cnt = (b < half) ? cntP : cntN;
  int* partial = (b < half) ? partP : partN;
  int bb = b % half;
  int t = threadIdx.x;
  int sum = 0;
#pragma unroll
  for (int i = 0; i < 4; i++) {
    int idx = bb * 1024 + i * 256 + t;
    if (idx < N) sum += cnt[idx];
  }
#pragma unroll
  for (int o = 32; o; o >>= 1) sum += __shfl_xor(sum, o);
  __shared__ int sh[4];
  if ((t & 63) == 0) sh[t >> 6] = sum;
  __syncthreads();
  if (t == 0) partial[bb] = sh[0] + sh[1] + sh[2] + sh[3];
}

__global__ __launch_bounds__(64) void k_scan_top2(const int* __restrict__ partP, const int* __restrict__ partN,
                                                  int* __restrict__ prefP, int* __restrict__ prefN,
                                                  int nb, int* __restrict__ offPN, int* __restrict__ offNN, int total) {
  const int* partial = (blockIdx.x == 0) ? partP : partN;
  int* pref = (blockIdx.x == 0) ? prefP : prefN;
  int* offN = (blockIdx.x == 0) ? offPN : offNN;
  int l = threadIdx.x;
  int v = (l < nb) ? partial[l] : 0;
  int x = v;
#pragma unroll
  for (int o = 1; o < 64; o <<= 1) {
    int y = __shfl_up(x, o);
    if (l >= o) x += y;
  }
  if (l < nb) pref[l] = x - v;  // exclusive
  if (l == 0) *offN = total;
}

__global__ __launch_bounds__(256) void k_scan_final2(const int* __restrict__ cntP, const int* __restrict__ cntN,
                                                     const int* __restrict__ prefP, const int* __restrict__ prefN,
                                                     int* __restrict__ offP, int* __restrict__ offN,
                                                     int N, int half) {
  int b = blockIdx.x;
  const int* cnt = (b < half) ? cntP : cntN;
  const int* pref = (b < half) ? prefP : prefN;
  int* off = (b < half) ? offP : offN;
  int bb = b % half;
  int t = threadIdx.x;
  int idx0 = bb * 1024 + t * 4;
  int v0 = (idx0 + 0 < N) ? cnt[idx0 + 0] : 0;
  int v1 = (idx0 + 1 < N) ? cnt[idx0 + 1] : 0;
  int v2 = (idx0 + 2 < N) ? cnt[idx0 + 2] : 0;
  int v3 = (idx0 + 3 < N) ? cnt[idx0 + 3] : 0;
  int s = v0 + v1 + v2 + v3;
  int lane = t & 63, w = t >> 6;
  int x = s;
#pragma unroll
  for (int o = 1; o < 64; o <<= 1) {
    int y = __shfl_up(x, o);
    if (lane >= o) x += y;
  }
  __shared__ int wtot[4];
  if (lane == 63) wtot[w] = x;
  __syncthreads();
  int woff = 0;
#pragma unroll
  for (int i = 0; i < 4; i++)
    if (i < w) woff += wtot[i];
  int excl = pref[bb] + woff + (x - s);
  if (idx0 + 0 < N) off[idx0 + 0] = excl;
  excl += v0;
  if (idx0 + 1 < N) off[idx0 + 1] = excl;
  excl += v1;
  if (idx0 + 2 < N) off[idx0 + 2] = excl;
  excl += v2;
  if (idx0 + 3 < N) off[idx0 + 3] = excl;
}

__global__ __launch_bounds__(256) void k_scatter2(const int* __restrict__ ep, const int* __restrict__ en,
                                                  const int* __restrict__ offP, const int* __restrict__ offN,
                                                  int* __restrict__ cntP, int* __restrict__ cntN,
                                                  int* __restrict__ srtP, int* __restrict__ srtN, int E, int half) {
  int b = blockIdx.x;
  const int* ei = (b < half) ? ep : en;
  const int* off = (b < half) ? offP : offN;
  int* cnt = (b < half) ? cntP : cntN;
  int* srt = (b < half) ? srtP : srtN;
  int e = (b % half) * 256 + threadIdx.x;
  if (e < E) {
    int s = ei[e], d = ei[E + e];
    int p = atomicSub(&cnt[d], 1) - 1;  // reuses histogram, ends at zero
    srt[off[d] + p] = s;
  }
}

// ---------------- prep: x -> bf16, W -> fragment-order bf16 ----------------
// x region: blocks [0, 3125): 8 floats/thread.
// W0 region: blocks [3125, 3157): 8192 threads -> (g,n,ks,lane) frags, K=128.
// W1 region: blocks [3157, 3173): 4096 threads, K=256.

__global__ __launch_bounds__(256) void k_prep(const float* __restrict__ x,
                                              const float* __restrict__ W0p, const float* __restrict__ W0n,
                                              const float* __restrict__ W1p, const float* __restrict__ W1n,
                                              unsigned short* __restrict__ xb,
                                              unsigned short* __restrict__ w0f,
                                              unsigned short* __restrict__ w1f) {
  int b = blockIdx.x, t = threadIdx.x;
  if (b < 3125) {
    int base = (b * 256 + t) * 8;
    float4 v0 = *(const float4*)&x[base];
    float4 v1 = *(const float4*)&x[base + 4];
    ushort4 a, c;
    a.x = f2b(v0.x); a.y = f2b(v0.y); a.z = f2b(v0.z); a.w = f2b(v0.w);
    c.x = f2b(v1.x); c.y = f2b(v1.y); c.z = f2b(v1.z); c.w = f2b(v1.w);
    *(ushort4*)&xb[base] = a;
    *(ushort4*)&xb[base + 4] = c;
  } else if (b < 3157) {
    int tid = (b - 3125) * 256 + t;  // 0..8191
    int lane = tid & 63;
    int rest = tid >> 6;
    int ks = rest & 3; rest >>= 2;
    int n = rest & 3;
    int g = rest >> 2;  // 0..7
    int col = (g & 3) * 64 + n * 16 + (lane & 15);
    const float* W = (g < 4) ? W0p : W0n;
    size_t dst = ((((size_t)(g * 4 + n)) * 4 + ks) * 64 + lane) * 8;
#pragma unroll
    for (int j = 0; j < 8; j++) {
      int k = ks * 32 + (lane >> 4) * 8 + j;
      w0f[dst + j] = f2b(W[k * 256 + col]);
    }
  } else {
    int tid = (b - 3157) * 256 + t;  // 0..4095
    int lane = tid & 63;
    int rest = tid >> 6;
    int ks = rest & 7; rest >>= 3;
    int n = rest & 3;
    int g = rest >> 2;  // 0..1
    int col = n * 16 + (lane & 15);
    const float* W = g ? W1n : W1p;
    size_t dst = ((((size_t)(g * 4 + n)) * 8 + ks) * 64 + lane) * 8;
#pragma unroll
    for (int j = 0; j < 8; j++) {
      int k = ks * 32 + (lane >> 4) * 8 + j;
      w1f[dst + j] = f2b(W[k * 64 + col]);
    }
  }
}

// ---------------- MFMA GEMM: C[N x NC] = Abf16[N x K] @ Bfrag, + att dots ----------------
// block: 128 rows x 64 cols (one col-group g = one head-half); 4 waves along M (32 rows each).
// wave tile 32x64 = 2(mi) x 4(n) frags of 16x16; K-loop in 32-steps.
// A frag: lane reads Ab[row=(row0+mi*16+(lane&15))][ks*32+(lane>>4)*8 ..+8] (bf16x8, 16B).
// B frag: pre-swizzled, Bv[((g*4+n)*KSTEPS+ks)*64+lane].
// C/D layout (m89-verified): col=lane&15, row=(lane>>4)*4+reg.
// Epilogue: att dots from fp32 acc: per (mi,reg) reduce over 4 n-frags x 16 lanes.

template <int KSTEPS, int CBF16, int H, int NC>
__global__ __launch_bounds__(256) void k_mgemm(const unsigned short* __restrict__ Ab,
                                               const unsigned short* __restrict__ Bf,
                                               unsigned short* __restrict__ Cb, float* __restrict__ Cf,
                                               int Nrows,
                                               const float* __restrict__ attSP, const float* __restrict__ attDP,
                                               const float* __restrict__ attSN, const float* __restrict__ attDN,
                                               float* __restrict__ oSP, float* __restrict__ oDP,
                                               float* __restrict__ oSN, float* __restrict__ oDN) {
  constexpr int K = KSTEPS * 32;
  int wm = threadIdx.x >> 6, lane = threadIdx.x & 63;
  int row0 = blockIdx.x * 128 + wm * 32;
  int g = blockIdx.y;
  const bf16x8* Bv = (const bf16x8*)Bf;
  const bf16x8* Av = (const bf16x8*)Ab;  // row stride K/8 vecs

  f32x4 acc[2][4];
#pragma unroll
  for (int mi = 0; mi < 2; mi++)
#pragma unroll
    for (int n = 0; n < 4; n++) acc[mi][n] = (f32x4){0.f, 0.f, 0.f, 0.f};

  int r0 = row0 + (lane & 15);
  int r1 = r0 + 16;
  bool v0 = r0 < Nrows, v1 = r1 < Nrows;
  size_t arow0 = (size_t)r0 * (K / 8) + (lane >> 4);
  size_t arow1 = (size_t)r1 * (K / 8) + (lane >> 4);
  const bf16x8 az = {0, 0, 0, 0, 0, 0, 0, 0};

  for (int kh = 0; kh < KSTEPS / 4; kh++) {
#pragma unroll
    for (int k4 = 0; k4 < 4; k4++) {
      int ks = kh * 4 + k4;
      bf16x8 a0 = v0 ? Av[arow0 + ks * 4] : az;
      bf16x8 a1 = v1 ? Av[arow1 + ks * 4] : az;
      bf16x8 b0 = Bv[((size_t)(g * 4 + 0) * KSTEPS + ks) * 64 + lane];
      bf16x8 b1 = Bv[((size_t)(g * 4 + 1) * KSTEPS + ks) * 64 + lane];
      bf16x8 b2 = Bv[((size_t)(g * 4 + 2) * KSTEPS + ks) * 64 + lane];
      bf16x8 b3 = Bv[((size_t)(g * 4 + 3) * KSTEPS + ks) * 64 + lane];
      acc[0][0] = __builtin_amdgcn_mfma_f32_16x16x32_bf16(a0, b0, acc[0][0], 0, 0, 0);
      acc[0][1] = __builtin_amdgcn_mfma_f32_16x16x32_bf16(a0, b1, acc[0][1], 0, 0, 0);
      acc[0][2] = __builtin_amdgcn_mfma_f32_16x16x32_bf16(a0, b2, acc[0][2], 0, 0, 0);
      acc[0][3] = __builtin_amdgcn_mfma_f32_16x16x32_bf16(a0, b3, acc[0][3], 0, 0, 0);
      acc[1][0] = __builtin_amdgcn_mfma_f32_16x16x32_bf16(a1, b0, acc[1][0], 0, 0, 0);
      acc[1][1] = __builtin_amdgcn_mfma_f32_16x16x32_bf16(a1, b1, acc[1][1], 0, 0, 0);
      acc[1][2] = __builtin_amdgcn_mfma_f32_16x16x32_bf16(a1, b2, acc[1][2], 0, 0, 0);
      acc[1][3] = __builtin_amdgcn_mfma_f32_16x16x32_bf16(a1, b3, acc[1][3], 0, 0, 0);
    }
  }

  // C store
#pragma unroll
  for (int mi = 0; mi < 2; mi++)
#pragma unroll
    for (int n = 0; n < 4; n++)
#pragma unroll
      for (int reg = 0; reg < 4; reg++) {
        int row = row0 + mi * 16 + (lane >> 4) * 4 + reg;
        int col = g * 64 + n * 16 + (lane & 15);
        if (row < Nrows) {
          if (CBF16)
            Cb[(size_t)row * NC + col] = f2b(acc[mi][n][reg]);
          else
            Cf[(size_t)row * NC + col] = acc[mi][n][reg];
        }
      }

  // att dots
  constexpr int POSG = NC / 128;  // pos col-groups
  int isNeg = (g >= POSG) ? 1 : 0;
  int head = isNeg ? g - POSG : g;
  const float* wS = (isNeg ? attSN : attSP) + head * 64;
  const float* wD = (isNeg ? attDN : attDP) + head * 64;
  float* oS = isNeg ? oSN : oSP;
  float* oD = isNeg ? oDN : oDP;
  float ws0 = wS[0 * 16 + (lane & 15)], ws1 = wS[1 * 16 + (lane & 15)];
  float ws2 = wS[2 * 16 + (lane & 15)], ws3 = wS[3 * 16 + (lane & 15)];
  float wd0 = wD[0 * 16 + (lane & 15)], wd1 = wD[1 * 16 + (lane & 15)];
  float wd2 = wD[2 * 16 + (lane & 15)], wd3 = wD[3 * 16 + (lane & 15)];
#pragma unroll
  for (int mi = 0; mi < 2; mi++)
#pragma unroll
    for (int reg = 0; reg < 4; reg++) {
      float ps = acc[mi][0][reg] * ws0 + acc[mi][1][reg] * ws1 + acc[mi][2][reg] * ws2 + acc[mi][3][reg] * ws3;
      float pd = acc[mi][0][reg] * wd0 + acc[mi][1][reg] * wd1 + acc[mi][2][reg] * wd2 + acc[mi][3][reg] * wd3;
#pragma unroll
      for (int o = 1; o < 16; o <<= 1) {
        ps += __shfl_xor(ps, o);
        pd += __shfl_xor(pd, o);
      }
      int row = row0 + mi * 16 + (lane >> 4) * 4 + reg;
      if ((lane & 15) == 0 && row < Nrows) {
        oS[(size_t)row * H + head] = ps;
        oD[(size_t)row * H + head] = pd;
      }
    }
}

// ---------------- softmax stats (layer 0: 4 heads) ----------------

struct MS4 { float m0, m1, m2, m3, s0, s1, s2, s3; };

__device__ __forceinline__ MS4 stats_heads(const float* __restrict__ as, float4 sl, float4 ad,
                                           const int* __restrict__ srt, int base, int deg, int l) {
  MS4 r;
  r.m0 = r.m1 = r.m2 = r.m3 = -1e30f;
  r.s0 = r.s1 = r.s2 = r.s3 = 0.f;
  if (l == 0) {  // self edge seeds lane 0
    r.m0 = lrelu(sl.x + ad.x); r.s0 = 1.f;
    r.m1 = lrelu(sl.y + ad.y); r.s1 = 1.f;
    r.m2 = lrelu(sl.z + ad.z); r.s2 = 1.f;
    r.m3 = lrelu(sl.w + ad.w); r.s3 = 1.f;
  }
  for (int i = l; i < deg; i += 64) {
    int s = srt[base + i];
    float4 av = *(const float4*)&as[(size_t)s * 4];
    onup(r.m0, r.s0, lrelu(av.x + ad.x));
    onup(r.m1, r.s1, lrelu(av.y + ad.y));
    onup(r.m2, r.s2, lrelu(av.z + ad.z));
    onup(r.m3, r.s3, lrelu(av.w + ad.w));
  }
#pragma unroll
  for (int o = 32; o; o >>= 1) {
    float mo, so, nm;
    mo = __shfl_xor(r.m0, o); so = __shfl_xor(r.s0, o);
    nm = fmaxf(r.m0, mo); r.s0 = r.s0 * __expf(r.m0 - nm) + so * __expf(mo - nm); r.m0 = nm;
    mo = __shfl_xor(r.m1, o); so = __shfl_xor(r.s1, o);
    nm = fmaxf(r.m1, mo); r.s1 = r.s1 * __expf(r.m1 - nm) + so * __expf(mo - nm); r.m1 = nm;
    mo = __shfl_xor(r.m2, o); so = __shfl_xor(r.s2, o);
    nm = fmaxf(r.m2, mo); r.s2 = r.s2 * __expf(r.m2 - nm) + so * __expf(mo - nm); r.m2 = nm;
    mo = __shfl_xor(r.m3, o); so = __shfl_xor(r.s3, o);
    nm = fmaxf(r.m3, mo); r.s3 = r.s3 * __expf(r.m3 - nm) + so * __expf(mo - nm); r.m3 = nm;
  }
  return r;
}

// ---------------- fused layer-0 aggregation: bf16 h0, inline weights, 8-way MLP ----------------

__device__ __forceinline__ float4 gather0b(const unsigned short* __restrict__ h0b, int colElem,
                                           const float* __restrict__ as, int hl, float adh,
                                           float mh, float inv, float wself, int n,
                                           const int* __restrict__ srt, int base, int deg, int l) {
  float4 acc;
  {
    uint2 hv = *(const uint2*)&h0b[(size_t)n * 512 + colElem];
    acc.x = wself * blo(hv.x); acc.y = wself * bhi(hv.x);
    acc.z = wself * blo(hv.y); acc.w = wself * bhi(hv.y);
  }
  for (int j = 0; j < deg; j += 8) {
    int idx[8];
    float w[8];
#pragma unroll
    for (int s2 = 0; s2 < 8; s2++) {
      int jj = j + s2;
      bool v = jj < deg;
      int p = base + (v ? jj : 0);
      int si = srt[p];
      idx[s2] = si;
      float e = lrelu(as[(size_t)si * 4 + hl] + adh);
      w[s2] = v ? __expf(e - mh) * inv : 0.f;
    }
#pragma unroll
    for (int s2 = 0; s2 < 8; s2++) {
      uint2 hv = *(const uint2*)&h0b[(size_t)idx[s2] * 512 + colElem];
      acc.x = fmaf(w[s2], blo(hv.x), acc.x);
      acc.y = fmaf(w[s2], bhi(hv.x), acc.y);
      acc.z = fmaf(w[s2], blo(hv.y), acc.z);
      acc.w = fmaf(w[s2], bhi(hv.y), acc.w);
    }
  }
  return acc;
}

__global__ __launch_bounds__(256) void k_agg0f(const unsigned short* __restrict__ h0b,
                                               const float* __restrict__ asP, const float* __restrict__ adP,
                                               const float* __restrict__ asN, const float* __restrict__ adN,
                                               const int* __restrict__ offP, const int* __restrict__ srtP,
                                               const int* __restrict__ offN, const int* __restrict__ srtN,
                                               const float* __restrict__ bP, const float* __restrict__ bN,
                                               unsigned short* __restrict__ xb, int N) {
  int n = blockIdx.x * 4 + (threadIdx.x >> 6);
  if (n >= N) return;
  int l = threadIdx.x & 63;
  int hl = l >> 4;

  int baseP = offP[n], degP = offP[n + 1] - baseP;
  float4 adp4 = *(const float4*)&adP[(size_t)n * 4];
  float4 asp4 = *(const float4*)&asP[(size_t)n * 4];
  MS4 P = stats_heads(asP, asp4, adp4, srtP, baseP, degP, l);
  float mhP = sel4(P.m0, P.m1, P.m2, P.m3, hl);
  float invP = 1.f / (sel4(P.s0, P.s1, P.s2, P.s3, hl) + 1e-16f);
  float adhP = sel4(adp4.x, adp4.y, adp4.z, adp4.w, hl);
  float ashP = sel4(asp4.x, asp4.y, asp4.z, asp4.w, hl);
  float wselfP = __expf(lrelu(ashP + adhP) - mhP) * invP;
  float4 accP = gather0b(h0b, l * 4, asP, hl, adhP, mhP, invP, wselfP, n, srtP, baseP, degP, l);

  int baseN = offN[n], degN = offN[n + 1] - baseN;
  float4 adn4 = *(const float4*)&adN[(size_t)n * 4];
  float4 asn4 = *(const float4*)&asN[(size_t)n * 4];
  MS4 Q = stats_heads(asN, asn4, adn4, srtN, baseN, degN, l);
  float mhN = sel4(Q.m0, Q.m1, Q.m2, Q.m3, hl);
  float invN = 1.f / (sel4(Q.s0, Q.s1, Q.s2, Q.s3, hl) + 1e-16f);
  float adhN = sel4(adn4.x, adn4.y, adn4.z, adn4.w, hl);
  float ashN = sel4(asn4.x, asn4.y, asn4.z, asn4.w, hl);
  float wselfN = __expf(lrelu(ashN + adhN) - mhN) * invN;
  float4 accN = gather0b(h0b, 256 + l * 4, asN, hl, adhN, mhN, invN, wselfN, n, srtN, baseN, degN, l);

  float4 bp = *(const float4*)&bP[l * 4];
  float4 bn = *(const float4*)&bN[l * 4];
  float rx = accP.x + bp.x - accN.x - bn.x;
  float ry = accP.y + bp.y - accN.y - bn.y;
  float rz = accP.z + bp.z - accN.z - bn.z;
  float rw = accP.w + bp.w - accN.w - bn.w;
  rx = rx > 0.f ? rx : expm1f(rx);
  ry = ry > 0.f ? ry : expm1f(ry);
  rz = rz > 0.f ? rz : expm1f(rz);
  rw = rw > 0.f ? rw : expm1f(rw);
  ushort4 r;
  r.x = f2b(rx); r.y = f2b(ry); r.z = f2b(rz); r.w = f2b(rw);
  *(ushort4*)&xb[(size_t)n * 256 + l * 4] = r;
}

// ---------------- fused layer-1 aggregation (fp32 h1), as round 3 ----------------

__device__ __forceinline__ void stats1(const float* __restrict__ as, float sl, float ad,
                                       const int* __restrict__ srt, int base, int deg, int l,
                                       float& m, float& s) {
  m = -1e30f;
  s = 0.f;
  if (l == 0) {
    m = lrelu(sl + ad);
    s = 1.f;
  }
  for (int i = l; i < deg; i += 64) onup(m, s, lrelu(as[srt[base + i]] + ad));
#pragma unroll
  for (int o = 32; o; o >>= 1) {
    float mo = __shfl_xor(m, o);
    float so = __shfl_xor(s, o);
    float nm = fmaxf(m, mo);
    s = s * __expf(m - nm) + so * __expf(mo - nm);
    m = nm;
  }
}

__device__ __forceinline__ float gather1_half(const float* __restrict__ h1, int colOff,
                                              const float* __restrict__ as, float ad, float mh, float inv,
                                              float wself, int n, const int* __restrict__ srt, int base, int deg,
                                              int l) {
  float acc = wself * h1[(size_t)n * 128 + colOff + l];
  for (int j = 0; j < deg; j += 8) {
    int idx[8];
    float w[8];
#pragma unroll
    for (int s2 = 0; s2 < 8; s2++) {
      int jj = j + s2;
      bool v = jj < deg;
      int p = base + (v ? jj : 0);
      int si = srt[p];
      idx[s2] = si;
      w[s2] = v ? __expf(lrelu(as[si] + ad) - mh) * inv : 0.f;
    }
#pragma unroll
    for (int s2 = 0; s2 < 8; s2++) acc = fmaf(w[s2], h1[(size_t)idx[s2] * 128 + colOff + l], acc);
  }
  return acc;
}

__global__ __launch_bounds__(256) void k_agg1f(const float* __restrict__ h1,
                                               const float* __restrict__ asP, const float* __restrict__ adP,
                                               const float* __restrict__ asN, const float* __restrict__ adN,
                                               const int* __restrict__ offP, const int* __restrict__ srtP,
                                               const int* __restrict__ offN, const int* __restrict__ srtN,
                                               const float* __restrict__ bP, const float* __restrict__ bN,
                                               float* __restrict__ out, int N) {
  int n = blockIdx.x * 4 + (threadIdx.x >> 6);
  if (n >= N) return;
  int l = threadIdx.x & 63;

  int baseP = offP[n], degP = offP[n + 1] - baseP;
  float adp = adP[n], asp = asP[n];
  float mP, sP;
  stats1(asP, asp, adp, srtP, baseP, degP, l, mP, sP);
  float invP = 1.f / (sP + 1e-16f);
  float wselfP = __expf(lrelu(asp + adp) - mP) * invP;
  float accP = gather1_half(h1, 0, asP, adp, mP, invP, wselfP, n, srtP, baseP, degP, l);

  int baseN = offN[n], degN = offN[n + 1] - baseN;
  float adn = adN[n], asn = asN[n];
  float mN, sN;
  stats1(asN, asn, adn, srtN, baseN, degN, l, mN, sN);
  float invN = 1.f / (sN + 1e-16f);
  float wselfN = __expf(lrelu(asn + adn) - mN) * invN;
  float accN = gather1_half(h1, 64, asN, adn, mN, invN, wselfN, n, srtN, baseN, degN, l);

  out[(size_t)n * 64 + l] = (accP + bP[l]) - (accN + bN[l]);
}

// ---------------- launch ----------------

extern "C" void kernel_launch(void* const* d_in, const int* in_sizes, int n_in,
                              void* d_out, int out_size, void* d_ws, size_t ws_size,
                              hipStream_t stream) {
  const float* x = (const float*)d_in[0];
  const int* ep = (const int*)d_in[1];
  const int* en = (const int*)d_in[2];
  const float* W0p = (const float*)d_in[3];
  const float* asrc0p = (const float*)d_in[4];
  const float* adst0p = (const float*)d_in[5];
  const float* b0p = (const float*)d_in[6];
  const float* W0n = (const float*)d_in[7];
  const float* asrc0n = (const float*)d_in[8];
  const float* adst0n = (const float*)d_in[9];
  const float* b0n = (const float*)d_in[10];
  const float* W1p = (const float*)d_in[11];
  const float* asrc1p = (const float*)d_in[12];
  const float* adst1p = (const float*)d_in[13];
  const float* b1p = (const float*)d_in[14];
  const float* W1n = (const float*)d_in[15];
  const float* asrc1n = (const float*)d_in[16];
  const float* adst1n = (const float*)d_in[17];
  const float* b1n = (const float*)d_in[18];

  const int N = N_NODES, E = N_EDGES;
  char* base = (char*)d_ws;
  size_t o = 0;
  auto alloc = [&](size_t bytes) -> void* {
    void* r = base + o;
    o = (o + bytes + 255) & ~(size_t)255;
    return r;
  };
  int* cnt_p = (int*)alloc((size_t)N * 4);
  int* cnt_n = (int*)alloc((size_t)N * 4);
  size_t cntBytes = o;  // memset covers both count arrays (+padding)
  int* off_p = (int*)alloc((size_t)(N + 1) * 4);
  int* off_n = (int*)alloc((size_t)(N + 1) * 4);
  int* part_p = (int*)alloc(1024 * 4);
  int* part_n = (int*)alloc(1024 * 4);
  int* pref_p = (int*)alloc(1024 * 4);
  int* pref_n = (int*)alloc(1024 * 4);
  int* srt_p = (int*)alloc((size_t)E * 4);
  int* srt_n = (int*)alloc((size_t)E * 4);
  unsigned short* xb16 = (unsigned short*)alloc((size_t)N * 128 * 2);
  unsigned short* w0f = (unsigned short*)alloc(65536 * 2);
  unsigned short* w1f = (unsigned short*)alloc(32768 * 2);
  unsigned short* h0b = (unsigned short*)alloc((size_t)N * 512 * 2);
  float* as0p = (float*)alloc((size_t)N * 4 * 4);
  float* ad0p = (float*)alloc((size_t)N * 4 * 4);
  float* as0n = (float*)alloc((size_t)N * 4 * 4);
  float* ad0n = (float*)alloc((size_t)N * 4 * 4);
  float* as1p = (float*)alloc((size_t)N * 4);
  float* ad1p = (float*)alloc((size_t)N * 4);
  float* as1n = (float*)alloc((size_t)N * 4);
  float* ad1n = (float*)alloc((size_t)N * 4);
  unsigned short* xbufb = (unsigned short*)alloc((size_t)N * 256 * 2);
  float* h1 = (float*)alloc((size_t)N * 128 * 4);

  hipMemsetAsync(base, 0, cntBytes, stream);

  int egrid = (E + 255) / 256;
  int nb = (N + 1023) / 1024;  // 49
  k_hist2<<<2 * egrid, 256, 0, stream>>>(ep, en, cnt_p, cnt_n, E, egrid);
  k_scan_partial2<<<2 * nb, 256, 0, stream>>>(cnt_p, cnt_n, part_p, part_n, N, nb);
  k_scan_top2<<<2, 64, 0, stream>>>(part_p, part_n, pref_p, pref_n, nb, off_p + N, off_n + N, E);
  k_scan_final2<<<2 * nb, 256, 0, stream>>>(cnt_p, cnt_n, pref_p, pref_n, off_p, off_n, N, nb);
  k_scatter2<<<2 * egrid, 256, 0, stream>>>(ep, en, off_p, off_n, cnt_p, cnt_n, srt_p, srt_n, E, egrid);

  k_prep<<<3173, 256, 0, stream>>>(x, W0p, W0n, W1p, W1n, xb16, w0f, w1f);

  int ngrid = (N + 3) / 4;
  int mgrid = (N + 127) / 128;  // 391

  // layer 0: MFMA GEMM (bf16 C + att dots) then fused aggregation
  dim3 g0(mgrid, 8);
  k_mgemm<4, 1, 4, 512><<<g0, 256, 0, stream>>>(xb16, w0f, h0b, (float*)nullptr, N,
                                                asrc0p, adst0p, asrc0n, adst0n,
                                                as0p, ad0p, as0n, ad0n);
  k_agg0f<<<ngrid, 256, 0, stream>>>(h0b, as0p, ad0p, as0n, ad0n,
                                     off_p, srt_p, off_n, srt_n, b0p, b0n, xbufb, N);

  // layer 1: MFMA GEMM (fp32 C + att dots) then fused aggregation
  dim3 g1(mgrid, 2);
  k_mgemm<8, 0, 1, 128><<<g1, 256, 0, stream>>>(xbufb, w1f, (unsigned short*)nullptr, h1, N,
                                                asrc1p, adst1p, asrc1n, adst1n,
                                                as1p, ad1p, as1n, ad1n);
  k_agg1f<<<ngrid, 256, 0, stream>>>(h1, as1p, ad1p, as1n, ad1n,
                                     off_p, srt_p, off_n, srt_n, b1p, b1n, (float*)d_out, N);
}

// Round 7
// 577.660 us; speedup vs baseline: 1.4672x; 1.1041x over previous
//
#include <hip/hip_runtime.h>
#include <cstdint>

#define N_NODES 50000
#define N_EDGES 800000

typedef __attribute__((ext_vector_type(8))) short bf16x8;
typedef __attribute__((ext_vector_type(4))) float f32x4;

__device__ __forceinline__ float lrelu(float x) { return x >= 0.f ? x : 0.2f * x; }

__device__ __forceinline__ unsigned short f2b(float f) {  // fp32 -> bf16 RNE
  unsigned int u = __float_as_uint(f);
  u += 0x7FFFu + ((u >> 16) & 1u);
  return (unsigned short)(u >> 16);
}
__device__ __forceinline__ float blo(unsigned int u) { return __uint_as_float(u << 16); }
__device__ __forceinline__ float bhi(unsigned int u) { return __uint_as_float(u & 0xFFFF0000u); }

// ---------------- CSR build (pos+neg merged per kernel) ----------------

__global__ __launch_bounds__(256) void k_hist2(const int* __restrict__ ep, const int* __restrict__ en,
                                               int* __restrict__ cntP, int* __restrict__ cntN, int E, int half) {
  int b = blockIdx.x;
  const int* ei = (b < half) ? ep : en;
  int* cnt = (b < half) ? cntP : cntN;
  int e = (b % half) * 256 + threadIdx.x;
  if (e < E) atomicAdd(&cnt[ei[E + e]], 1);
}

__global__ __launch_bounds__(256) void k_scan_partial2(const int* __restrict__ cntP, const int* __restrict__ cntN,
                                                       int* __restrict__ partP, int* __restrict__ partN,
                                                       int N, int half) {
  int b = blockIdx.x;
  const int* cnt = (b < half) ? cntP : cntN;
  int* partial = (b < half) ? partP : partN;
  int bb = b % half;
  int t = threadIdx.x;
  int sum = 0;
#pragma unroll
  for (int i = 0; i < 4; i++) {
    int idx = bb * 1024 + i * 256 + t;
    if (idx < N) sum += cnt[idx];
  }
#pragma unroll
  for (int o = 32; o; o >>= 1) sum += __shfl_xor(sum, o);
  __shared__ int sh[4];
  if ((t & 63) == 0) sh[t >> 6] = sum;
  __syncthreads();
  if (t == 0) partial[bb] = sh[0] + sh[1] + sh[2] + sh[3];
}

__global__ __launch_bounds__(64) void k_scan_top2(const int* __restrict__ partP, const int* __restrict__ partN,
                                                  int* __restrict__ prefP, int* __restrict__ prefN,
                                                  int nb, int* __restrict__ offPN, int* __restrict__ offNN, int total) {
  const int* partial = (blockIdx.x == 0) ? partP : partN;
  int* pref = (blockIdx.x == 0) ? prefP : prefN;
  int* offN = (blockIdx.x == 0) ? offPN : offNN;
  int l = threadIdx.x;
  int v = (l < nb) ? partial[l] : 0;
  int x = v;
#pragma unroll
  for (int o = 1; o < 64; o <<= 1) {
    int y = __shfl_up(x, o);
    if (l >= o) x += y;
  }
  if (l < nb) pref[l] = x - v;  // exclusive
  if (l == 0) *offN = total;
}

__global__ __launch_bounds__(256) void k_scan_final2(const int* __restrict__ cntP, const int* __restrict__ cntN,
                                                     const int* __restrict__ prefP, const int* __restrict__ prefN,
                                                     int* __restrict__ offP, int* __restrict__ offN,
                                                     int N, int half) {
  int b = blockIdx.x;
  const int* cnt = (b < half) ? cntP : cntN;
  const int* pref = (b < half) ? prefP : prefN;
  int* off = (b < half) ? offP : offN;
  int bb = b % half;
  int t = threadIdx.x;
  int idx0 = bb * 1024 + t * 4;
  int v0 = (idx0 + 0 < N) ? cnt[idx0 + 0] : 0;
  int v1 = (idx0 + 1 < N) ? cnt[idx0 + 1] : 0;
  int v2 = (idx0 + 2 < N) ? cnt[idx0 + 2] : 0;
  int v3 = (idx0 + 3 < N) ? cnt[idx0 + 3] : 0;
  int s = v0 + v1 + v2 + v3;
  int lane = t & 63, w = t >> 6;
  int x = s;
#pragma unroll
  for (int o = 1; o < 64; o <<= 1) {
    int y = __shfl_up(x, o);
    if (lane >= o) x += y;
  }
  __shared__ int wtot[4];
  if (lane == 63) wtot[w] = x;
  __syncthreads();
  int woff = 0;
#pragma unroll
  for (int i = 0; i < 4; i++)
    if (i < w) woff += wtot[i];
  int excl = pref[bb] + woff + (x - s);
  if (idx0 + 0 < N) off[idx0 + 0] = excl;
  excl += v0;
  if (idx0 + 1 < N) off[idx0 + 1] = excl;
  excl += v1;
  if (idx0 + 2 < N) off[idx0 + 2] = excl;
  excl += v2;
  if (idx0 + 3 < N) off[idx0 + 3] = excl;
}

__global__ __launch_bounds__(256) void k_scatter2(const int* __restrict__ ep, const int* __restrict__ en,
                                                  const int* __restrict__ offP, const int* __restrict__ offN,
                                                  int* __restrict__ cntP, int* __restrict__ cntN,
                                                  int* __restrict__ srtP, int* __restrict__ srtN, int E, int half) {
  int b = blockIdx.x;
  const int* ei = (b < half) ? ep : en;
  const int* off = (b < half) ? offP : offN;
  int* cnt = (b < half) ? cntP : cntN;
  int* srt = (b < half) ? srtP : srtN;
  int e = (b % half) * 256 + threadIdx.x;
  if (e < E) {
    int s = ei[e], d = ei[E + e];
    int p = atomicSub(&cnt[d], 1) - 1;  // reuses histogram, ends at zero
    srt[off[d] + p] = s;
  }
}

// ---------------- prep: x -> bf16, W -> fragment-order bf16 ----------------

__global__ __launch_bounds__(256) void k_prep(const float* __restrict__ x,
                                              const float* __restrict__ W0p, const float* __restrict__ W0n,
                                              const float* __restrict__ W1p, const float* __restrict__ W1n,
                                              unsigned short* __restrict__ xb,
                                              unsigned short* __restrict__ w0f,
                                              unsigned short* __restrict__ w1f) {
  int b = blockIdx.x, t = threadIdx.x;
  if (b < 3125) {
    int base = (b * 256 + t) * 8;
    float4 v0 = *(const float4*)&x[base];
    float4 v1 = *(const float4*)&x[base + 4];
    ushort4 a, c;
    a.x = f2b(v0.x); a.y = f2b(v0.y); a.z = f2b(v0.z); a.w = f2b(v0.w);
    c.x = f2b(v1.x); c.y = f2b(v1.y); c.z = f2b(v1.z); c.w = f2b(v1.w);
    *(ushort4*)&xb[base] = a;
    *(ushort4*)&xb[base + 4] = c;
  } else if (b < 3157) {
    int tid = (b - 3125) * 256 + t;  // 0..8191
    int lane = tid & 63;
    int rest = tid >> 6;
    int ks = rest & 3; rest >>= 2;
    int n = rest & 3;
    int g = rest >> 2;  // 0..7
    int col = (g & 3) * 64 + n * 16 + (lane & 15);
    const float* W = (g < 4) ? W0p : W0n;
    size_t dst = ((((size_t)(g * 4 + n)) * 4 + ks) * 64 + lane) * 8;
#pragma unroll
    for (int j = 0; j < 8; j++) {
      int k = ks * 32 + (lane >> 4) * 8 + j;
      w0f[dst + j] = f2b(W[k * 256 + col]);
    }
  } else {
    int tid = (b - 3157) * 256 + t;  // 0..4095
    int lane = tid & 63;
    int rest = tid >> 6;
    int ks = rest & 7; rest >>= 3;
    int n = rest & 3;
    int g = rest >> 2;  // 0..1
    int col = n * 16 + (lane & 15);
    const float* W = g ? W1n : W1p;
    size_t dst = ((((size_t)(g * 4 + n)) * 8 + ks) * 64 + lane) * 8;
#pragma unroll
    for (int j = 0; j < 8; j++) {
      int k = ks * 32 + (lane >> 4) * 8 + j;
      w1f[dst + j] = f2b(W[k * 64 + col]);
    }
  }
}

// ---------------- MFMA GEMM: C[N x NC] = Abf16[N x K] @ Bfrag, + att dots ----------------

template <int KSTEPS, int CBF16, int H, int NC>
__global__ __launch_bounds__(256) void k_mgemm(const unsigned short* __restrict__ Ab,
                                               const unsigned short* __restrict__ Bf,
                                               unsigned short* __restrict__ Cb, float* __restrict__ Cf,
                                               int Nrows,
                                               const float* __restrict__ attSP, const float* __restrict__ attDP,
                                               const float* __restrict__ attSN, const float* __restrict__ attDN,
                                               float* __restrict__ oSP, float* __restrict__ oDP,
                                               float* __restrict__ oSN, float* __restrict__ oDN) {
  constexpr int K = KSTEPS * 32;
  int wm = threadIdx.x >> 6, lane = threadIdx.x & 63;
  int row0 = blockIdx.x * 128 + wm * 32;
  int g = blockIdx.y;
  const bf16x8* Bv = (const bf16x8*)Bf;
  const bf16x8* Av = (const bf16x8*)Ab;  // row stride K/8 vecs

  f32x4 acc[2][4];
#pragma unroll
  for (int mi = 0; mi < 2; mi++)
#pragma unroll
    for (int n = 0; n < 4; n++) acc[mi][n] = (f32x4){0.f, 0.f, 0.f, 0.f};

  int r0 = row0 + (lane & 15);
  int r1 = r0 + 16;
  bool v0 = r0 < Nrows, v1 = r1 < Nrows;
  size_t arow0 = (size_t)r0 * (K / 8) + (lane >> 4);
  size_t arow1 = (size_t)r1 * (K / 8) + (lane >> 4);
  const bf16x8 az = {0, 0, 0, 0, 0, 0, 0, 0};

  for (int kh = 0; kh < KSTEPS / 4; kh++) {
#pragma unroll
    for (int k4 = 0; k4 < 4; k4++) {
      int ks = kh * 4 + k4;
      bf16x8 a0 = v0 ? Av[arow0 + ks * 4] : az;
      bf16x8 a1 = v1 ? Av[arow1 + ks * 4] : az;
      bf16x8 b0 = Bv[((size_t)(g * 4 + 0) * KSTEPS + ks) * 64 + lane];
      bf16x8 b1 = Bv[((size_t)(g * 4 + 1) * KSTEPS + ks) * 64 + lane];
      bf16x8 b2 = Bv[((size_t)(g * 4 + 2) * KSTEPS + ks) * 64 + lane];
      bf16x8 b3 = Bv[((size_t)(g * 4 + 3) * KSTEPS + ks) * 64 + lane];
      acc[0][0] = __builtin_amdgcn_mfma_f32_16x16x32_bf16(a0, b0, acc[0][0], 0, 0, 0);
      acc[0][1] = __builtin_amdgcn_mfma_f32_16x16x32_bf16(a0, b1, acc[0][1], 0, 0, 0);
      acc[0][2] = __builtin_amdgcn_mfma_f32_16x16x32_bf16(a0, b2, acc[0][2], 0, 0, 0);
      acc[0][3] = __builtin_amdgcn_mfma_f32_16x16x32_bf16(a0, b3, acc[0][3], 0, 0, 0);
      acc[1][0] = __builtin_amdgcn_mfma_f32_16x16x32_bf16(a1, b0, acc[1][0], 0, 0, 0);
      acc[1][1] = __builtin_amdgcn_mfma_f32_16x16x32_bf16(a1, b1, acc[1][1], 0, 0, 0);
      acc[1][2] = __builtin_amdgcn_mfma_f32_16x16x32_bf16(a1, b2, acc[1][2], 0, 0, 0);
      acc[1][3] = __builtin_amdgcn_mfma_f32_16x16x32_bf16(a1, b3, acc[1][3], 0, 0, 0);
    }
  }

  // C store (C/D layout m89: col=lane&15, row=(lane>>4)*4+reg)
#pragma unroll
  for (int mi = 0; mi < 2; mi++)
#pragma unroll
    for (int n = 0; n < 4; n++)
#pragma unroll
      for (int reg = 0; reg < 4; reg++) {
        int row = row0 + mi * 16 + (lane >> 4) * 4 + reg;
        int col = g * 64 + n * 16 + (lane & 15);
        if (row < Nrows) {
          if (CBF16)
            Cb[(size_t)row * NC + col] = f2b(acc[mi][n][reg]);
          else
            Cf[(size_t)row * NC + col] = acc[mi][n][reg];
        }
      }

  // att dots
  constexpr int POSG = NC / 128;  // pos col-groups
  int isNeg = (g >= POSG) ? 1 : 0;
  int head = isNeg ? g - POSG : g;
  const float* wS = (isNeg ? attSN : attSP) + head * 64;
  const float* wD = (isNeg ? attDN : attDP) + head * 64;
  float* oS = isNeg ? oSN : oSP;
  float* oD = isNeg ? oDN : oDP;
  float ws0 = wS[0 * 16 + (lane & 15)], ws1 = wS[1 * 16 + (lane & 15)];
  float ws2 = wS[2 * 16 + (lane & 15)], ws3 = wS[3 * 16 + (lane & 15)];
  float wd0 = wD[0 * 16 + (lane & 15)], wd1 = wD[1 * 16 + (lane & 15)];
  float wd2 = wD[2 * 16 + (lane & 15)], wd3 = wD[3 * 16 + (lane & 15)];
#pragma unroll
  for (int mi = 0; mi < 2; mi++)
#pragma unroll
    for (int reg = 0; reg < 4; reg++) {
      float ps = acc[mi][0][reg] * ws0 + acc[mi][1][reg] * ws1 + acc[mi][2][reg] * ws2 + acc[mi][3][reg] * ws3;
      float pd = acc[mi][0][reg] * wd0 + acc[mi][1][reg] * wd1 + acc[mi][2][reg] * wd2 + acc[mi][3][reg] * wd3;
#pragma unroll
      for (int o = 1; o < 16; o <<= 1) {
        ps += __shfl_xor(ps, o);
        pd += __shfl_xor(pd, o);
      }
      int row = row0 + mi * 16 + (lane >> 4) * 4 + reg;
      if ((lane & 15) == 0 && row < Nrows) {
        oS[(size_t)row * H + head] = ps;
        oD[(size_t)row * H + head] = pd;
      }
    }
}

// ---------------- k_sa0: per-edge raw exp weights (no-max softmax) + per-node inv/self ----------------
// wave per node. alpha[e][h] = exp(lrelu(as[src]+ad[dst])); inv[n][h] = 1/(sum+selfex+eps);
// wslf[n][h] = selfex*inv. Gather then computes out = inv*sum(alpha*h) + wslf*h_self.

__global__ __launch_bounds__(256) void k_sa0(const float* __restrict__ asP, const float* __restrict__ adP,
                                             const int* __restrict__ offP, const int* __restrict__ srtP,
                                             float* __restrict__ alphaP, float* __restrict__ invP,
                                             float* __restrict__ wslfP,
                                             const float* __restrict__ asN, const float* __restrict__ adN,
                                             const int* __restrict__ offN, const int* __restrict__ srtN,
                                             float* __restrict__ alphaN, float* __restrict__ invN,
                                             float* __restrict__ wslfN, int N) {
  int n = blockIdx.x * 4 + (threadIdx.x >> 6);
  if (n >= N) return;
  int l = threadIdx.x & 63;
  {
    int base = offP[n], deg = offP[n + 1] - base;
    float4 ad4 = *(const float4*)&adP[(size_t)n * 4];
    float s0 = 0.f, s1 = 0.f, s2 = 0.f, s3 = 0.f;
    for (int i = l; i < deg; i += 64) {
      int s = srtP[base + i];
      float4 av = *(const float4*)&asP[(size_t)s * 4];
      float4 ex;
      ex.x = __expf(lrelu(av.x + ad4.x));
      ex.y = __expf(lrelu(av.y + ad4.y));
      ex.z = __expf(lrelu(av.z + ad4.z));
      ex.w = __expf(lrelu(av.w + ad4.w));
      *(float4*)&alphaP[(size_t)(base + i) * 4] = ex;
      s0 += ex.x; s1 += ex.y; s2 += ex.z; s3 += ex.w;
    }
#pragma unroll
    for (int o = 32; o; o >>= 1) {
      s0 += __shfl_xor(s0, o);
      s1 += __shfl_xor(s1, o);
      s2 += __shfl_xor(s2, o);
      s3 += __shfl_xor(s3, o);
    }
    if (l == 0) {
      float4 as4 = *(const float4*)&asP[(size_t)n * 4];
      float e0 = __expf(lrelu(as4.x + ad4.x));
      float e1 = __expf(lrelu(as4.y + ad4.y));
      float e2 = __expf(lrelu(as4.z + ad4.z));
      float e3 = __expf(lrelu(as4.w + ad4.w));
      float i0 = 1.f / (s0 + e0 + 1e-16f);
      float i1 = 1.f / (s1 + e1 + 1e-16f);
      float i2 = 1.f / (s2 + e2 + 1e-16f);
      float i3 = 1.f / (s3 + e3 + 1e-16f);
      *(float4*)&invP[(size_t)n * 4] = make_float4(i0, i1, i2, i3);
      *(float4*)&wslfP[(size_t)n * 4] = make_float4(e0 * i0, e1 * i1, e2 * i2, e3 * i3);
    }
  }
  {
    int base = offN[n], deg = offN[n + 1] - base;
    float4 ad4 = *(const float4*)&adN[(size_t)n * 4];
    float s0 = 0.f, s1 = 0.f, s2 = 0.f, s3 = 0.f;
    for (int i = l; i < deg; i += 64) {
      int s = srtN[base + i];
      float4 av = *(const float4*)&asN[(size_t)s * 4];
      float4 ex;
      ex.x = __expf(lrelu(av.x + ad4.x));
      ex.y = __expf(lrelu(av.y + ad4.y));
      ex.z = __expf(lrelu(av.z + ad4.z));
      ex.w = __expf(lrelu(av.w + ad4.w));
      *(float4*)&alphaN[(size_t)(base + i) * 4] = ex;
      s0 += ex.x; s1 += ex.y; s2 += ex.z; s3 += ex.w;
    }
#pragma unroll
    for (int o = 32; o; o >>= 1) {
      s0 += __shfl_xor(s0, o);
      s1 += __shfl_xor(s1, o);
      s2 += __shfl_xor(s2, o);
      s3 += __shfl_xor(s3, o);
    }
    if (l == 0) {
      float4 as4 = *(const float4*)&asN[(size_t)n * 4];
      float e0 = __expf(lrelu(as4.x + ad4.x));
      float e1 = __expf(lrelu(as4.y + ad4.y));
      float e2 = __expf(lrelu(as4.z + ad4.z));
      float e3 = __expf(lrelu(as4.w + ad4.w));
      float i0 = 1.f / (s0 + e0 + 1e-16f);
      float i1 = 1.f / (s1 + e1 + 1e-16f);
      float i2 = 1.f / (s2 + e2 + 1e-16f);
      float i3 = 1.f / (s3 + e3 + 1e-16f);
      *(float4*)&invN[(size_t)n * 4] = make_float4(i0, i1, i2, i3);
      *(float4*)&wslfN[(size_t)n * 4] = make_float4(e0 * i0, e1 * i1, e2 * i2, e3 * i3);
    }
  }
}

// ---------------- layer-0 gather: pure weighted sum of bf16 rows, scale at end ----------------

__device__ __forceinline__ float4 gather0b(const unsigned short* __restrict__ h0b, int colElem,
                                           const float* __restrict__ alpha, int hl,
                                           const int* __restrict__ srt, int base, int deg) {
  float4 acc = make_float4(0.f, 0.f, 0.f, 0.f);
  for (int j = 0; j < deg; j += 8) {
    int idx[8];
    float w[8];
#pragma unroll
    for (int s2 = 0; s2 < 8; s2++) {
      int jj = j + s2;
      bool v = jj < deg;
      int p = base + (v ? jj : 0);
      idx[s2] = srt[p];
      w[s2] = v ? alpha[(size_t)p * 4 + hl] : 0.f;
    }
#pragma unroll
    for (int s2 = 0; s2 < 8; s2++) {
      uint2 hv = *(const uint2*)&h0b[(size_t)idx[s2] * 512 + colElem];
      acc.x = fmaf(w[s2], blo(hv.x), acc.x);
      acc.y = fmaf(w[s2], bhi(hv.x), acc.y);
      acc.z = fmaf(w[s2], blo(hv.y), acc.z);
      acc.w = fmaf(w[s2], bhi(hv.y), acc.w);
    }
  }
  return acc;
}

__global__ __launch_bounds__(256) void k_gather0(const unsigned short* __restrict__ h0b,
                                                 const int* __restrict__ offP, const int* __restrict__ srtP,
                                                 const float* __restrict__ alphaP, const float* __restrict__ invP,
                                                 const float* __restrict__ wslfP,
                                                 const int* __restrict__ offN, const int* __restrict__ srtN,
                                                 const float* __restrict__ alphaN, const float* __restrict__ invN,
                                                 const float* __restrict__ wslfN,
                                                 const float* __restrict__ bP, const float* __restrict__ bN,
                                                 unsigned short* __restrict__ xb, int N) {
  int n = blockIdx.x * 4 + (threadIdx.x >> 6);
  if (n >= N) return;
  int l = threadIdx.x & 63;
  int hl = l >> 4;

  int baseP = offP[n], degP = offP[n + 1] - baseP;
  float4 accP = gather0b(h0b, l * 4, alphaP, hl, srtP, baseP, degP);
  {
    float iv = invP[(size_t)n * 4 + hl];
    float ws = wslfP[(size_t)n * 4 + hl];
    uint2 hs = *(const uint2*)&h0b[(size_t)n * 512 + l * 4];
    accP.x = fmaf(accP.x, iv, ws * blo(hs.x));
    accP.y = fmaf(accP.y, iv, ws * bhi(hs.x));
    accP.z = fmaf(accP.z, iv, ws * blo(hs.y));
    accP.w = fmaf(accP.w, iv, ws * bhi(hs.y));
  }

  int baseN = offN[n], degN = offN[n + 1] - baseN;
  float4 accN = gather0b(h0b, 256 + l * 4, alphaN, hl, srtN, baseN, degN);
  {
    float iv = invN[(size_t)n * 4 + hl];
    float ws = wslfN[(size_t)n * 4 + hl];
    uint2 hs = *(const uint2*)&h0b[(size_t)n * 512 + 256 + l * 4];
    accN.x = fmaf(accN.x, iv, ws * blo(hs.x));
    accN.y = fmaf(accN.y, iv, ws * bhi(hs.x));
    accN.z = fmaf(accN.z, iv, ws * blo(hs.y));
    accN.w = fmaf(accN.w, iv, ws * bhi(hs.y));
  }

  float4 bp = *(const float4*)&bP[l * 4];
  float4 bn = *(const float4*)&bN[l * 4];
  float rx = accP.x + bp.x - accN.x - bn.x;
  float ry = accP.y + bp.y - accN.y - bn.y;
  float rz = accP.z + bp.z - accN.z - bn.z;
  float rw = accP.w + bp.w - accN.w - bn.w;
  rx = rx > 0.f ? rx : expm1f(rx);
  ry = ry > 0.f ? ry : expm1f(ry);
  rz = rz > 0.f ? rz : expm1f(rz);
  rw = rw > 0.f ? rw : expm1f(rw);
  ushort4 r;
  r.x = f2b(rx); r.y = f2b(ry); r.z = f2b(rz); r.w = f2b(rw);
  *(ushort4*)&xb[(size_t)n * 256 + l * 4] = r;
}

// ---------------- k_sa1 / k_gather1 (1 head) ----------------

__global__ __launch_bounds__(256) void k_sa1(const float* __restrict__ asP, const float* __restrict__ adP,
                                             const int* __restrict__ offP, const int* __restrict__ srtP,
                                             float* __restrict__ alphaP, float* __restrict__ invP,
                                             float* __restrict__ wslfP,
                                             const float* __restrict__ asN, const float* __restrict__ adN,
                                             const int* __restrict__ offN, const int* __restrict__ srtN,
                                             float* __restrict__ alphaN, float* __restrict__ invN,
                                             float* __restrict__ wslfN, int N) {
  int n = blockIdx.x * 4 + (threadIdx.x >> 6);
  if (n >= N) return;
  int l = threadIdx.x & 63;
  {
    int base = offP[n], deg = offP[n + 1] - base;
    float ad = adP[n];
    float s = 0.f;
    for (int i = l; i < deg; i += 64) {
      float ex = __expf(lrelu(asP[srtP[base + i]] + ad));
      alphaP[base + i] = ex;
      s += ex;
    }
#pragma unroll
    for (int o = 32; o; o >>= 1) s += __shfl_xor(s, o);
    if (l == 0) {
      float se = __expf(lrelu(asP[n] + ad));
      float iv = 1.f / (s + se + 1e-16f);
      invP[n] = iv;
      wslfP[n] = se * iv;
    }
  }
  {
    int base = offN[n], deg = offN[n + 1] - base;
    float ad = adN[n];
    float s = 0.f;
    for (int i = l; i < deg; i += 64) {
      float ex = __expf(lrelu(asN[srtN[base + i]] + ad));
      alphaN[base + i] = ex;
      s += ex;
    }
#pragma unroll
    for (int o = 32; o; o >>= 1) s += __shfl_xor(s, o);
    if (l == 0) {
      float se = __expf(lrelu(asN[n] + ad));
      float iv = 1.f / (s + se + 1e-16f);
      invN[n] = iv;
      wslfN[n] = se * iv;
    }
  }
}

__device__ __forceinline__ float gather1b(const float* __restrict__ h1, int colIdx,
                                          const float* __restrict__ alpha,
                                          const int* __restrict__ srt, int base, int deg) {
  float acc = 0.f;
  for (int j = 0; j < deg; j += 8) {
    int idx[8];
    float w[8];
#pragma unroll
    for (int s2 = 0; s2 < 8; s2++) {
      int jj = j + s2;
      bool v = jj < deg;
      int p = base + (v ? jj : 0);
      idx[s2] = srt[p];
      w[s2] = v ? alpha[p] : 0.f;
    }
#pragma unroll
    for (int s2 = 0; s2 < 8; s2++) acc = fmaf(w[s2], h1[(size_t)idx[s2] * 128 + colIdx], acc);
  }
  return acc;
}

__global__ __launch_bounds__(256) void k_gather1(const float* __restrict__ h1,
                                                 const int* __restrict__ offP, const int* __restrict__ srtP,
                                                 const float* __restrict__ alphaP, const float* __restrict__ invP,
                                                 const float* __restrict__ wslfP,
                                                 const int* __restrict__ offN, const int* __restrict__ srtN,
                                                 const float* __restrict__ alphaN, const float* __restrict__ invN,
                                                 const float* __restrict__ wslfN,
                                                 const float* __restrict__ bP, const float* __restrict__ bN,
                                                 float* __restrict__ out, int N) {
  int n = blockIdx.x * 4 + (threadIdx.x >> 6);
  if (n >= N) return;
  int l = threadIdx.x & 63;

  int baseP = offP[n], degP = offP[n + 1] - baseP;
  float accP = gather1b(h1, l, alphaP, srtP, baseP, degP);
  accP = fmaf(accP, invP[n], wslfP[n] * h1[(size_t)n * 128 + l]);

  int baseN = offN[n], degN = offN[n + 1] - baseN;
  float accN = gather1b(h1, 64 + l, alphaN, srtN, baseN, degN);
  accN = fmaf(accN, invN[n], wslfN[n] * h1[(size_t)n * 128 + 64 + l]);

  out[(size_t)n * 64 + l] = (accP + bP[l]) - (accN + bN[l]);
}

// ---------------- launch ----------------

extern "C" void kernel_launch(void* const* d_in, const int* in_sizes, int n_in,
                              void* d_out, int out_size, void* d_ws, size_t ws_size,
                              hipStream_t stream) {
  const float* x = (const float*)d_in[0];
  const int* ep = (const int*)d_in[1];
  const int* en = (const int*)d_in[2];
  const float* W0p = (const float*)d_in[3];
  const float* asrc0p = (const float*)d_in[4];
  const float* adst0p = (const float*)d_in[5];
  const float* b0p = (const float*)d_in[6];
  const float* W0n = (const float*)d_in[7];
  const float* asrc0n = (const float*)d_in[8];
  const float* adst0n = (const float*)d_in[9];
  const float* b0n = (const float*)d_in[10];
  const float* W1p = (const float*)d_in[11];
  const float* asrc1p = (const float*)d_in[12];
  const float* adst1p = (const float*)d_in[13];
  const float* b1p = (const float*)d_in[14];
  const float* W1n = (const float*)d_in[15];
  const float* asrc1n = (const float*)d_in[16];
  const float* adst1n = (const float*)d_in[17];
  const float* b1n = (const float*)d_in[18];

  const int N = N_NODES, E = N_EDGES;
  char* base = (char*)d_ws;
  size_t o = 0;
  auto alloc = [&](size_t bytes) -> void* {
    void* r = base + o;
    o = (o + bytes + 255) & ~(size_t)255;
    return r;
  };
  int* cnt_p = (int*)alloc((size_t)N * 4);
  int* cnt_n = (int*)alloc((size_t)N * 4);
  size_t cntBytes = o;  // memset covers both count arrays (+padding)
  int* off_p = (int*)alloc((size_t)(N + 1) * 4);
  int* off_n = (int*)alloc((size_t)(N + 1) * 4);
  int* part_p = (int*)alloc(1024 * 4);
  int* part_n = (int*)alloc(1024 * 4);
  int* pref_p = (int*)alloc(1024 * 4);
  int* pref_n = (int*)alloc(1024 * 4);
  int* srt_p = (int*)alloc((size_t)E * 4);
  int* srt_n = (int*)alloc((size_t)E * 4);
  unsigned short* xb16 = (unsigned short*)alloc((size_t)N * 128 * 2);
  unsigned short* w0f = (unsigned short*)alloc(65536 * 2);
  unsigned short* w1f = (unsigned short*)alloc(32768 * 2);
  unsigned short* h0b = (unsigned short*)alloc((size_t)N * 512 * 2);
  float* as0p = (float*)alloc((size_t)N * 4 * 4);
  float* ad0p = (float*)alloc((size_t)N * 4 * 4);
  float* as0n = (float*)alloc((size_t)N * 4 * 4);
  float* ad0n = (float*)alloc((size_t)N * 4 * 4);
  float* as1p = (float*)alloc((size_t)N * 4);
  float* ad1p = (float*)alloc((size_t)N * 4);
  float* as1n = (float*)alloc((size_t)N * 4);
  float* ad1n = (float*)alloc((size_t)N * 4);
  float* inv0p = (float*)alloc((size_t)N * 4 * 4);
  float* wslf0p = (float*)alloc((size_t)N * 4 * 4);
  float* inv0n = (float*)alloc((size_t)N * 4 * 4);
  float* wslf0n = (float*)alloc((size_t)N * 4 * 4);
  float* inv1p = (float*)alloc((size_t)N * 4);
  float* wslf1p = (float*)alloc((size_t)N * 4);
  float* inv1n = (float*)alloc((size_t)N * 4);
  float* wslf1n = (float*)alloc((size_t)N * 4);
  float* alpha0p = (float*)alloc((size_t)E * 4 * 4);
  float* alpha0n = (float*)alloc((size_t)E * 4 * 4);
  float* alpha1p = (float*)alloc((size_t)E * 4);
  float* alpha1n = (float*)alloc((size_t)E * 4);
  unsigned short* xbufb = (unsigned short*)alloc((size_t)N * 256 * 2);
  float* h1 = (float*)alloc((size_t)N * 128 * 4);

  hipMemsetAsync(base, 0, cntBytes, stream);

  int egrid = (E + 255) / 256;
  int nb = (N + 1023) / 1024;  // 49
  k_hist2<<<2 * egrid, 256, 0, stream>>>(ep, en, cnt_p, cnt_n, E, egrid);
  k_scan_partial2<<<2 * nb, 256, 0, stream>>>(cnt_p, cnt_n, part_p, part_n, N, nb);
  k_scan_top2<<<2, 64, 0, stream>>>(part_p, part_n, pref_p, pref_n, nb, off_p + N, off_n + N, E);
  k_scan_final2<<<2 * nb, 256, 0, stream>>>(cnt_p, cnt_n, pref_p, pref_n, off_p, off_n, N, nb);
  k_scatter2<<<2 * egrid, 256, 0, stream>>>(ep, en, off_p, off_n, cnt_p, cnt_n, srt_p, srt_n, E, egrid);

  k_prep<<<3173, 256, 0, stream>>>(x, W0p, W0n, W1p, W1n, xb16, w0f, w1f);

  int ngrid = (N + 3) / 4;
  int mgrid = (N + 127) / 128;  // 391

  // layer 0
  dim3 g0(mgrid, 8);
  k_mgemm<4, 1, 4, 512><<<g0, 256, 0, stream>>>(xb16, w0f, h0b, (float*)nullptr, N,
                                                asrc0p, adst0p, asrc0n, adst0n,
                                                as0p, ad0p, as0n, ad0n);
  k_sa0<<<ngrid, 256, 0, stream>>>(as0p, ad0p, off_p, srt_p, alpha0p, inv0p, wslf0p,
                                   as0n, ad0n, off_n, srt_n, alpha0n, inv0n, wslf0n, N);
  k_gather0<<<ngrid, 256, 0, stream>>>(h0b, off_p, srt_p, alpha0p, inv0p, wslf0p,
                                       off_n, srt_n, alpha0n, inv0n, wslf0n, b0p, b0n, xbufb, N);

  // layer 1
  dim3 g1(mgrid, 2);
  k_mgemm<8, 0, 1, 128><<<g1, 256, 0, stream>>>(xbufb, w1f, (unsigned short*)nullptr, h1, N,
                                                asrc1p, adst1p, asrc1n, adst1n,
                                                as1p, ad1p, as1n, ad1n);
  k_sa1<<<ngrid, 256, 0, stream>>>(as1p, ad1p, off_p, srt_p, alpha1p, inv1p, wslf1p,
                                   as1n, ad1n, off_n, srt_n, alpha1n, inv1n, wslf1n, N);
  k_gather1<<<ngrid, 256, 0, stream>>>(h1, off_p, srt_p, alpha1p, inv1p, wslf1p,
                                       off_n, srt_n, alpha1n, inv1n, wslf1n, b1p, b1n, (float*)d_out, N);
}

// Round 9
// 575.247 us; speedup vs baseline: 1.4733x; 1.0042x over previous
//
#include <hip/hip_runtime.h>
#include <cstdint>

#define N_NODES 50000
#define N_EDGES 800000

typedef __attribute__((ext_vector_type(8))) short bf16x8;
typedef __attribute__((ext_vector_type(4))) float f32x4;

__device__ __forceinline__ float lrelu(float x) { return x >= 0.f ? x : 0.2f * x; }

__device__ __forceinline__ unsigned short f2b(float f) {  // fp32 -> bf16 RNE
  unsigned int u = __float_as_uint(f);
  u += 0x7FFFu + ((u >> 16) & 1u);
  return (unsigned short)(u >> 16);
}
__device__ __forceinline__ float blo(unsigned int u) { return __uint_as_float(u << 16); }
__device__ __forceinline__ float bhi(unsigned int u) { return __uint_as_float(u & 0xFFFF0000u); }

// ---------------- CSR build (pos+neg merged per kernel) ----------------

__global__ __launch_bounds__(256) void k_hist2(const int* __restrict__ ep, const int* __restrict__ en,
                                               int* __restrict__ cntP, int* __restrict__ cntN, int E, int half) {
  int b = blockIdx.x;
  const int* ei = (b < half) ? ep : en;
  int* cnt = (b < half) ? cntP : cntN;
  int e = (b % half) * 256 + threadIdx.x;
  if (e < E) atomicAdd(&cnt[ei[E + e]], 1);
}

__global__ __launch_bounds__(256) void k_scan_partial2(const int* __restrict__ cntP, const int* __restrict__ cntN,
                                                       int* __restrict__ partP, int* __restrict__ partN,
                                                       int N, int half) {
  int b = blockIdx.x;
  const int* cnt = (b < half) ? cntP : cntN;
  int* partial = (b < half) ? partP : partN;
  int bb = b % half;
  int t = threadIdx.x;
  int sum = 0;
#pragma unroll
  for (int i = 0; i < 4; i++) {
    int idx = bb * 1024 + i * 256 + t;
    if (idx < N) sum += cnt[idx];
  }
#pragma unroll
  for (int o = 32; o; o >>= 1) sum += __shfl_xor(sum, o);
  __shared__ int sh[4];
  if ((t & 63) == 0) sh[t >> 6] = sum;
  __syncthreads();
  if (t == 0) partial[bb] = sh[0] + sh[1] + sh[2] + sh[3];
}

__global__ __launch_bounds__(64) void k_scan_top2(const int* __restrict__ partP, const int* __restrict__ partN,
                                                  int* __restrict__ prefP, int* __restrict__ prefN,
                                                  int nb, int* __restrict__ offPN, int* __restrict__ offNN, int total) {
  const int* partial = (blockIdx.x == 0) ? partP : partN;
  int* pref = (blockIdx.x == 0) ? prefP : prefN;
  int* offN = (blockIdx.x == 0) ? offPN : offNN;
  int l = threadIdx.x;
  int v = (l < nb) ? partial[l] : 0;
  int x = v;
#pragma unroll
  for (int o = 1; o < 64; o <<= 1) {
    int y = __shfl_up(x, o);
    if (l >= o) x += y;
  }
  if (l < nb) pref[l] = x - v;  // exclusive
  if (l == 0) *offN = total;
}

__global__ __launch_bounds__(256) void k_scan_final2(const int* __restrict__ cntP, const int* __restrict__ cntN,
                                                     const int* __restrict__ prefP, const int* __restrict__ prefN,
                                                     int* __restrict__ offP, int* __restrict__ offN,
                                                     int N, int half) {
  int b = blockIdx.x;
  const int* cnt = (b < half) ? cntP : cntN;
  const int* pref = (b < half) ? prefP : prefN;
  int* off = (b < half) ? offP : offN;
  int bb = b % half;
  int t = threadIdx.x;
  int idx0 = bb * 1024 + t * 4;
  int v0 = (idx0 + 0 < N) ? cnt[idx0 + 0] : 0;
  int v1 = (idx0 + 1 < N) ? cnt[idx0 + 1] : 0;
  int v2 = (idx0 + 2 < N) ? cnt[idx0 + 2] : 0;
  int v3 = (idx0 + 3 < N) ? cnt[idx0 + 3] : 0;
  int s = v0 + v1 + v2 + v3;
  int lane = t & 63, w = t >> 6;
  int x = s;
#pragma unroll
  for (int o = 1; o < 64; o <<= 1) {
    int y = __shfl_up(x, o);
    if (lane >= o) x += y;
  }
  __shared__ int wtot[4];
  if (lane == 63) wtot[w] = x;
  __syncthreads();
  int woff = 0;
#pragma unroll
  for (int i = 0; i < 4; i++)
    if (i < w) woff += wtot[i];
  int excl = pref[bb] + woff + (x - s);
  if (idx0 + 0 < N) off[idx0 + 0] = excl;
  excl += v0;
  if (idx0 + 1 < N) off[idx0 + 1] = excl;
  excl += v1;
  if (idx0 + 2 < N) off[idx0 + 2] = excl;
  excl += v2;
  if (idx0 + 3 < N) off[idx0 + 3] = excl;
}

__global__ __launch_bounds__(256) void k_scatter2(const int* __restrict__ ep, const int* __restrict__ en,
                                                  const int* __restrict__ offP, const int* __restrict__ offN,
                                                  int* __restrict__ cntP, int* __restrict__ cntN,
                                                  int* __restrict__ srtP, int* __restrict__ srtN, int E, int half) {
  int b = blockIdx.x;
  const int* ei = (b < half) ? ep : en;
  const int* off = (b < half) ? offP : offN;
  int* cnt = (b < half) ? cntP : cntN;
  int* srt = (b < half) ? srtP : srtN;
  int e = (b % half) * 256 + threadIdx.x;
  if (e < E) {
    int s = ei[e], d = ei[E + e];
    int p = atomicSub(&cnt[d], 1) - 1;  // reuses histogram, ends at zero
    srt[off[d] + p] = s;
  }
}

// ---------------- prep: x -> bf16, W -> fragment-order bf16 ----------------

__global__ __launch_bounds__(256) void k_prep(const float* __restrict__ x,
                                              const float* __restrict__ W0p, const float* __restrict__ W0n,
                                              const float* __restrict__ W1p, const float* __restrict__ W1n,
                                              unsigned short* __restrict__ xb,
                                              unsigned short* __restrict__ w0f,
                                              unsigned short* __restrict__ w1f) {
  int b = blockIdx.x, t = threadIdx.x;
  if (b < 3125) {
    int base = (b * 256 + t) * 8;
    float4 v0 = *(const float4*)&x[base];
    float4 v1 = *(const float4*)&x[base + 4];
    ushort4 a, c;
    a.x = f2b(v0.x); a.y = f2b(v0.y); a.z = f2b(v0.z); a.w = f2b(v0.w);
    c.x = f2b(v1.x); c.y = f2b(v1.y); c.z = f2b(v1.z); c.w = f2b(v1.w);
    *(ushort4*)&xb[base] = a;
    *(ushort4*)&xb[base + 4] = c;
  } else if (b < 3157) {
    int tid = (b - 3125) * 256 + t;  // 0..8191
    int lane = tid & 63;
    int rest = tid >> 6;
    int ks = rest & 3; rest >>= 2;
    int n = rest & 3;
    int g = rest >> 2;  // 0..7
    int col = (g & 3) * 64 + n * 16 + (lane & 15);
    const float* W = (g < 4) ? W0p : W0n;
    size_t dst = ((((size_t)(g * 4 + n)) * 4 + ks) * 64 + lane) * 8;
#pragma unroll
    for (int j = 0; j < 8; j++) {
      int k = ks * 32 + (lane >> 4) * 8 + j;
      w0f[dst + j] = f2b(W[k * 256 + col]);
    }
  } else {
    int tid = (b - 3157) * 256 + t;  // 0..4095
    int lane = tid & 63;
    int rest = tid >> 6;
    int ks = rest & 7; rest >>= 3;
    int n = rest & 3;
    int g = rest >> 2;  // 0..1
    int col = n * 16 + (lane & 15);
    const float* W = g ? W1n : W1p;
    size_t dst = ((((size_t)(g * 4 + n)) * 8 + ks) * 64 + lane) * 8;
#pragma unroll
    for (int j = 0; j < 8; j++) {
      int k = ks * 32 + (lane >> 4) * 8 + j;
      w1f[dst + j] = f2b(W[k * 64 + col]);
    }
  }
}

// ---------------- MFMA GEMM: C[N x NC] = Abf16[N x K] @ Bfrag, + att dots ----------------
// Waves arranged (WROWS x WCOLS): wave handles 32 rows x one 64-col group.
// Col-groups within a block share A rows through L1 (A HBM traffic = gridDim.y passes).

template <int KSTEPS, int CBF16, int H, int NC, int WROWS, int WCOLS>
__global__ __launch_bounds__(256) void k_mgemm(const unsigned short* __restrict__ Ab,
                                               const unsigned short* __restrict__ Bf,
                                               unsigned short* __restrict__ Cb, float* __restrict__ Cf,
                                               int Nrows,
                                               const float* __restrict__ attSP, const float* __restrict__ attDP,
                                               const float* __restrict__ attSN, const float* __restrict__ attDN,
                                               float* __restrict__ oSP, float* __restrict__ oDP,
                                               float* __restrict__ oSN, float* __restrict__ oDN) {
  constexpr int K = KSTEPS * 32;
  int w = threadIdx.x >> 6, lane = threadIdx.x & 63;
  int wr = w / WCOLS, wc = w % WCOLS;
  int row0 = blockIdx.x * (WROWS * 32) + wr * 32;
  int g = blockIdx.y * WCOLS + wc;
  const bf16x8* Bv = (const bf16x8*)Bf;
  const bf16x8* Av = (const bf16x8*)Ab;  // row stride K/8 vecs

  f32x4 acc[2][4];
#pragma unroll
  for (int mi = 0; mi < 2; mi++)
#pragma unroll
    for (int n = 0; n < 4; n++) acc[mi][n] = (f32x4){0.f, 0.f, 0.f, 0.f};

  int r0 = row0 + (lane & 15);
  int r1 = r0 + 16;
  bool v0 = r0 < Nrows, v1 = r1 < Nrows;
  size_t arow0 = (size_t)r0 * (K / 8) + (lane >> 4);
  size_t arow1 = (size_t)r1 * (K / 8) + (lane >> 4);
  const bf16x8 az = {0, 0, 0, 0, 0, 0, 0, 0};

  for (int kh = 0; kh < KSTEPS / 4; kh++) {
#pragma unroll
    for (int k4 = 0; k4 < 4; k4++) {
      int ks = kh * 4 + k4;
      bf16x8 a0 = v0 ? Av[arow0 + ks * 4] : az;
      bf16x8 a1 = v1 ? Av[arow1 + ks * 4] : az;
      bf16x8 b0 = Bv[((size_t)(g * 4 + 0) * KSTEPS + ks) * 64 + lane];
      bf16x8 b1 = Bv[((size_t)(g * 4 + 1) * KSTEPS + ks) * 64 + lane];
      bf16x8 b2 = Bv[((size_t)(g * 4 + 2) * KSTEPS + ks) * 64 + lane];
      bf16x8 b3 = Bv[((size_t)(g * 4 + 3) * KSTEPS + ks) * 64 + lane];
      acc[0][0] = __builtin_amdgcn_mfma_f32_16x16x32_bf16(a0, b0, acc[0][0], 0, 0, 0);
      acc[0][1] = __builtin_amdgcn_mfma_f32_16x16x32_bf16(a0, b1, acc[0][1], 0, 0, 0);
      acc[0][2] = __builtin_amdgcn_mfma_f32_16x16x32_bf16(a0, b2, acc[0][2], 0, 0, 0);
      acc[0][3] = __builtin_amdgcn_mfma_f32_16x16x32_bf16(a0, b3, acc[0][3], 0, 0, 0);
      acc[1][0] = __builtin_amdgcn_mfma_f32_16x16x32_bf16(a1, b0, acc[1][0], 0, 0, 0);
      acc[1][1] = __builtin_amdgcn_mfma_f32_16x16x32_bf16(a1, b1, acc[1][1], 0, 0, 0);
      acc[1][2] = __builtin_amdgcn_mfma_f32_16x16x32_bf16(a1, b2, acc[1][2], 0, 0, 0);
      acc[1][3] = __builtin_amdgcn_mfma_f32_16x16x32_bf16(a1, b3, acc[1][3], 0, 0, 0);
    }
  }

  // C store (C/D layout m89: col=lane&15, row=(lane>>4)*4+reg)
#pragma unroll
  for (int mi = 0; mi < 2; mi++)
#pragma unroll
    for (int n = 0; n < 4; n++)
#pragma unroll
      for (int reg = 0; reg < 4; reg++) {
        int row = row0 + mi * 16 + (lane >> 4) * 4 + reg;
        int col = g * 64 + n * 16 + (lane & 15);
        if (row < Nrows) {
          if (CBF16)
            Cb[(size_t)row * NC + col] = f2b(acc[mi][n][reg]);
          else
            Cf[(size_t)row * NC + col] = acc[mi][n][reg];
        }
      }

  // att dots
  constexpr int POSG = NC / 128;  // pos col-groups
  int isNeg = (g >= POSG) ? 1 : 0;
  int head = isNeg ? g - POSG : g;
  const float* wS = (isNeg ? attSN : attSP) + head * 64;
  const float* wD = (isNeg ? attDN : attDP) + head * 64;
  float* oS = isNeg ? oSN : oSP;
  float* oD = isNeg ? oDN : oDP;
  float ws0 = wS[0 * 16 + (lane & 15)], ws1 = wS[1 * 16 + (lane & 15)];
  float ws2 = wS[2 * 16 + (lane & 15)], ws3 = wS[3 * 16 + (lane & 15)];
  float wd0 = wD[0 * 16 + (lane & 15)], wd1 = wD[1 * 16 + (lane & 15)];
  float wd2 = wD[2 * 16 + (lane & 15)], wd3 = wD[3 * 16 + (lane & 15)];
#pragma unroll
  for (int mi = 0; mi < 2; mi++)
#pragma unroll
    for (int reg = 0; reg < 4; reg++) {
      float ps = acc[mi][0][reg] * ws0 + acc[mi][1][reg] * ws1 + acc[mi][2][reg] * ws2 + acc[mi][3][reg] * ws3;
      float pd = acc[mi][0][reg] * wd0 + acc[mi][1][reg] * wd1 + acc[mi][2][reg] * wd2 + acc[mi][3][reg] * wd3;
#pragma unroll
      for (int o = 1; o < 16; o <<= 1) {
        ps += __shfl_xor(ps, o);
        pd += __shfl_xor(pd, o);
      }
      int row = row0 + mi * 16 + (lane >> 4) * 4 + reg;
      if ((lane & 15) == 0 && row < Nrows) {
        oS[(size_t)row * H + head] = ps;
        oD[(size_t)row * H + head] = pd;
      }
    }
}

// ---------------- k_sa0: per-edge raw exp weights (no-max softmax) + per-node inv/self ----------------

__global__ __launch_bounds__(256) void k_sa0(const float* __restrict__ asP, const float* __restrict__ adP,
                                             const int* __restrict__ offP, const int* __restrict__ srtP,
                                             float* __restrict__ alphaP, float* __restrict__ invP,
                                             float* __restrict__ wslfP,
                                             const float* __restrict__ asN, const float* __restrict__ adN,
                                             const int* __restrict__ offN, const int* __restrict__ srtN,
                                             float* __restrict__ alphaN, float* __restrict__ invN,
                                             float* __restrict__ wslfN, int N) {
  int n = blockIdx.x * 4 + (threadIdx.x >> 6);
  if (n >= N) return;
  int l = threadIdx.x & 63;
  {
    int base = offP[n], deg = offP[n + 1] - base;
    float4 ad4 = *(const float4*)&adP[(size_t)n * 4];
    float s0 = 0.f, s1 = 0.f, s2 = 0.f, s3 = 0.f;
    for (int i = l; i < deg; i += 64) {
      int s = srtP[base + i];
      float4 av = *(const float4*)&asP[(size_t)s * 4];
      float4 ex;
      ex.x = __expf(lrelu(av.x + ad4.x));
      ex.y = __expf(lrelu(av.y + ad4.y));
      ex.z = __expf(lrelu(av.z + ad4.z));
      ex.w = __expf(lrelu(av.w + ad4.w));
      *(float4*)&alphaP[(size_t)(base + i) * 4] = ex;
      s0 += ex.x; s1 += ex.y; s2 += ex.z; s3 += ex.w;
    }
#pragma unroll
    for (int o = 32; o; o >>= 1) {
      s0 += __shfl_xor(s0, o);
      s1 += __shfl_xor(s1, o);
      s2 += __shfl_xor(s2, o);
      s3 += __shfl_xor(s3, o);
    }
    if (l == 0) {
      float4 as4 = *(const float4*)&asP[(size_t)n * 4];
      float e0 = __expf(lrelu(as4.x + ad4.x));
      float e1 = __expf(lrelu(as4.y + ad4.y));
      float e2 = __expf(lrelu(as4.z + ad4.z));
      float e3 = __expf(lrelu(as4.w + ad4.w));
      float i0 = 1.f / (s0 + e0 + 1e-16f);
      float i1 = 1.f / (s1 + e1 + 1e-16f);
      float i2 = 1.f / (s2 + e2 + 1e-16f);
      float i3 = 1.f / (s3 + e3 + 1e-16f);
      *(float4*)&invP[(size_t)n * 4] = make_float4(i0, i1, i2, i3);
      *(float4*)&wslfP[(size_t)n * 4] = make_float4(e0 * i0, e1 * i1, e2 * i2, e3 * i3);
    }
  }
  {
    int base = offN[n], deg = offN[n + 1] - base;
    float4 ad4 = *(const float4*)&adN[(size_t)n * 4];
    float s0 = 0.f, s1 = 0.f, s2 = 0.f, s3 = 0.f;
    for (int i = l; i < deg; i += 64) {
      int s = srtN[base + i];
      float4 av = *(const float4*)&asN[(size_t)s * 4];
      float4 ex;
      ex.x = __expf(lrelu(av.x + ad4.x));
      ex.y = __expf(lrelu(av.y + ad4.y));
      ex.z = __expf(lrelu(av.z + ad4.z));
      ex.w = __expf(lrelu(av.w + ad4.w));
      *(float4*)&alphaN[(size_t)(base + i) * 4] = ex;
      s0 += ex.x; s1 += ex.y; s2 += ex.z; s3 += ex.w;
    }
#pragma unroll
    for (int o = 32; o; o >>= 1) {
      s0 += __shfl_xor(s0, o);
      s1 += __shfl_xor(s1, o);
      s2 += __shfl_xor(s2, o);
      s3 += __shfl_xor(s3, o);
    }
    if (l == 0) {
      float4 as4 = *(const float4*)&asN[(size_t)n * 4];
      float e0 = __expf(lrelu(as4.x + ad4.x));
      float e1 = __expf(lrelu(as4.y + ad4.y));
      float e2 = __expf(lrelu(as4.z + ad4.z));
      float e3 = __expf(lrelu(as4.w + ad4.w));
      float i0 = 1.f / (s0 + e0 + 1e-16f);
      float i1 = 1.f / (s1 + e1 + 1e-16f);
      float i2 = 1.f / (s2 + e2 + 1e-16f);
      float i3 = 1.f / (s3 + e3 + 1e-16f);
      *(float4*)&invN[(size_t)n * 4] = make_float4(i0, i1, i2, i3);
      *(float4*)&wslfN[(size_t)n * 4] = make_float4(e0 * i0, e1 * i1, e2 * i2, e3 * i3);
    }
  }
}

// ---------------- layer-0 gather: P/N interleaved (16 outstanding loads/wave) ----------------

__global__ __launch_bounds__(256) void k_gather0(const unsigned short* __restrict__ h0b,
                                                 const int* __restrict__ offP, const int* __restrict__ srtP,
                                                 const float* __restrict__ alphaP, const float* __restrict__ invP,
                                                 const float* __restrict__ wslfP,
                                                 const int* __restrict__ offN, const int* __restrict__ srtN,
                                                 const float* __restrict__ alphaN, const float* __restrict__ invN,
                                                 const float* __restrict__ wslfN,
                                                 const float* __restrict__ bP, const float* __restrict__ bN,
                                                 unsigned short* __restrict__ xb, int N) {
  int n = blockIdx.x * 4 + (threadIdx.x >> 6);
  if (n >= N) return;
  int l = threadIdx.x & 63;
  int hl = l >> 4;
  int colP = l * 4, colN = 256 + l * 4;

  int baseP = offP[n], degP = offP[n + 1] - baseP;
  int baseN = offN[n], degN = offN[n + 1] - baseN;
  float4 accP = make_float4(0.f, 0.f, 0.f, 0.f);
  float4 accN = make_float4(0.f, 0.f, 0.f, 0.f);
  int dmax = degP > degN ? degP : degN;
  for (int j = 0; j < dmax; j += 8) {
    int iP[8], iN[8];
    float wP[8], wN[8];
#pragma unroll
    for (int s = 0; s < 8; s++) {
      int jj = j + s;
      bool vP = jj < degP;
      int pP = vP ? baseP + jj : 0;  // pos 0 always valid; weight 0 kills contribution
      iP[s] = srtP[pP];
      wP[s] = vP ? alphaP[(size_t)pP * 4 + hl] : 0.f;
      bool vN = jj < degN;
      int pN = vN ? baseN + jj : 0;
      iN[s] = srtN[pN];
      wN[s] = vN ? alphaN[(size_t)pN * 4 + hl] : 0.f;
    }
#pragma unroll
    for (int s = 0; s < 8; s++) {
      uint2 hvP = *(const uint2*)&h0b[(size_t)iP[s] * 512 + colP];
      uint2 hvN = *(const uint2*)&h0b[(size_t)iN[s] * 512 + colN];
      accP.x = fmaf(wP[s], blo(hvP.x), accP.x);
      accP.y = fmaf(wP[s], bhi(hvP.x), accP.y);
      accP.z = fmaf(wP[s], blo(hvP.y), accP.z);
      accP.w = fmaf(wP[s], bhi(hvP.y), accP.w);
      accN.x = fmaf(wN[s], blo(hvN.x), accN.x);
      accN.y = fmaf(wN[s], bhi(hvN.x), accN.y);
      accN.z = fmaf(wN[s], blo(hvN.y), accN.z);
      accN.w = fmaf(wN[s], bhi(hvN.y), accN.w);
    }
  }
  {
    float iv = invP[(size_t)n * 4 + hl];
    float ws = wslfP[(size_t)n * 4 + hl];
    uint2 hs = *(const uint2*)&h0b[(size_t)n * 512 + colP];
    accP.x = fmaf(accP.x, iv, ws * blo(hs.x));
    accP.y = fmaf(accP.y, iv, ws * bhi(hs.x));
    accP.z = fmaf(accP.z, iv, ws * blo(hs.y));
    accP.w = fmaf(accP.w, iv, ws * bhi(hs.y));
  }
  {
    float iv = invN[(size_t)n * 4 + hl];
    float ws = wslfN[(size_t)n * 4 + hl];
    uint2 hs = *(const uint2*)&h0b[(size_t)n * 512 + colN];
    accN.x = fmaf(accN.x, iv, ws * blo(hs.x));
    accN.y = fmaf(accN.y, iv, ws * bhi(hs.x));
    accN.z = fmaf(accN.z, iv, ws * blo(hs.y));
    accN.w = fmaf(accN.w, iv, ws * bhi(hs.y));
  }

  float4 bp = *(const float4*)&bP[l * 4];
  float4 bn = *(const float4*)&bN[l * 4];
  float rx = accP.x + bp.x - accN.x - bn.x;
  float ry = accP.y + bp.y - accN.y - bn.y;
  float rz = accP.z + bp.z - accN.z - bn.z;
  float rw = accP.w + bp.w - accN.w - bn.w;
  rx = rx > 0.f ? rx : expm1f(rx);
  ry = ry > 0.f ? ry : expm1f(ry);
  rz = rz > 0.f ? rz : expm1f(rz);
  rw = rw > 0.f ? rw : expm1f(rw);
  ushort4 r;
  r.x = f2b(rx); r.y = f2b(ry); r.z = f2b(rz); r.w = f2b(rw);
  *(ushort4*)&xb[(size_t)n * 256 + l * 4] = r;
}

// ---------------- k_sa1 / k_gather1 (1 head), P/N interleaved gather ----------------

__global__ __launch_bounds__(256) void k_sa1(const float* __restrict__ asP, const float* __restrict__ adP,
                                             const int* __restrict__ offP, const int* __restrict__ srtP,
                                             float* __restrict__ alphaP, float* __restrict__ invP,
                                             float* __restrict__ wslfP,
                                             const float* __restrict__ asN, const float* __restrict__ adN,
                                             const int* __restrict__ offN, const int* __restrict__ srtN,
                                             float* __restrict__ alphaN, float* __restrict__ invN,
                                             float* __restrict__ wslfN, int N) {
  int n = blockIdx.x * 4 + (threadIdx.x >> 6);
  if (n >= N) return;
  int l = threadIdx.x & 63;
  {
    int base = offP[n], deg = offP[n + 1] - base;
    float ad = adP[n];
    float s = 0.f;
    for (int i = l; i < deg; i += 64) {
      float ex = __expf(lrelu(asP[srtP[base + i]] + ad));
      alphaP[base + i] = ex;
      s += ex;
    }
#pragma unroll
    for (int o = 32; o; o >>= 1) s += __shfl_xor(s, o);
    if (l == 0) {
      float se = __expf(lrelu(asP[n] + ad));
      float iv = 1.f / (s + se + 1e-16f);
      invP[n] = iv;
      wslfP[n] = se * iv;
    }
  }
  {
    int base = offN[n], deg = offN[n + 1] - base;
    float ad = adN[n];
    float s = 0.f;
    for (int i = l; i < deg; i += 64) {
      float ex = __expf(lrelu(asN[srtN[base + i]] + ad));
      alphaN[base + i] = ex;
      s += ex;
    }
#pragma unroll
    for (int o = 32; o; o >>= 1) s += __shfl_xor(s, o);
    if (l == 0) {
      float se = __expf(lrelu(asN[n] + ad));
      float iv = 1.f / (s + se + 1e-16f);
      invN[n] = iv;
      wslfN[n] = se * iv;
    }
  }
}

__global__ __launch_bounds__(256) void k_gather1(const float* __restrict__ h1,
                                                 const int* __restrict__ offP, const int* __restrict__ srtP,
                                                 const float* __restrict__ alphaP, const float* __restrict__ invP,
                                                 const float* __restrict__ wslfP,
                                                 const int* __restrict__ offN, const int* __restrict__ srtN,
                                                 const float* __restrict__ alphaN, const float* __restrict__ invN,
                                                 const float* __restrict__ wslfN,
                                                 const float* __restrict__ bP, const float* __restrict__ bN,
                                                 float* __restrict__ out, int N) {
  int n = blockIdx.x * 4 + (threadIdx.x >> 6);
  if (n >= N) return;
  int l = threadIdx.x & 63;

  int baseP = offP[n], degP = offP[n + 1] - baseP;
  int baseN = offN[n], degN = offN[n + 1] - baseN;
  float accP = 0.f, accN = 0.f;
  int dmax = degP > degN ? degP : degN;
  for (int j = 0; j < dmax; j += 8) {
    int iP[8], iN[8];
    float wP[8], wN[8];
#pragma unroll
    for (int s = 0; s < 8; s++) {
      int jj = j + s;
      bool vP = jj < degP;
      int pP = vP ? baseP + jj : 0;
      iP[s] = srtP[pP];
      wP[s] = vP ? alphaP[pP] : 0.f;
      bool vN = jj < degN;
      int pN = vN ? baseN + jj : 0;
      iN[s] = srtN[pN];
      wN[s] = vN ? alphaN[pN] : 0.f;
    }
#pragma unroll
    for (int s = 0; s < 8; s++) {
      accP = fmaf(wP[s], h1[(size_t)iP[s] * 128 + l], accP);
      accN = fmaf(wN[s], h1[(size_t)iN[s] * 128 + 64 + l], accN);
    }
  }
  accP = fmaf(accP, invP[n], wslfP[n] * h1[(size_t)n * 128 + l]);
  accN = fmaf(accN, invN[n], wslfN[n] * h1[(size_t)n * 128 + 64 + l]);

  out[(size_t)n * 64 + l] = (accP + bP[l]) - (accN + bN[l]);
}

// ---------------- launch ----------------

extern "C" void kernel_launch(void* const* d_in, const int* in_sizes, int n_in,
                              void* d_out, int out_size, void* d_ws, size_t ws_size,
                              hipStream_t stream) {
  const float* x = (const float*)d_in[0];
  const int* ep = (const int*)d_in[1];
  const int* en = (const int*)d_in[2];
  const float* W0p = (const float*)d_in[3];
  const float* asrc0p = (const float*)d_in[4];
  const float* adst0p = (const float*)d_in[5];
  const float* b0p = (const float*)d_in[6];
  const float* W0n = (const float*)d_in[7];
  const float* asrc0n = (const float*)d_in[8];
  const float* adst0n = (const float*)d_in[9];
  const float* b0n = (const float*)d_in[10];
  const float* W1p = (const float*)d_in[11];
  const float* asrc1p = (const float*)d_in[12];
  const float* adst1p = (const float*)d_in[13];
  const float* b1p = (const float*)d_in[14];
  const float* W1n = (const float*)d_in[15];
  const float* asrc1n = (const float*)d_in[16];
  const float* adst1n = (const float*)d_in[17];
  const float* b1n = (const float*)d_in[18];

  const int N = N_NODES, E = N_EDGES;
  char* base = (char*)d_ws;
  size_t o = 0;
  auto alloc = [&](size_t bytes) -> void* {
    void* r = base + o;
    o = (o + bytes + 255) & ~(size_t)255;
    return r;
  };
  int* cnt_p = (int*)alloc((size_t)N * 4);
  int* cnt_n = (int*)alloc((size_t)N * 4);
  size_t cntBytes = o;  // memset covers both count arrays (+padding)
  int* off_p = (int*)alloc((size_t)(N + 1) * 4);
  int* off_n = (int*)alloc((size_t)(N + 1) * 4);
  int* part_p = (int*)alloc(1024 * 4);
  int* part_n = (int*)alloc(1024 * 4);
  int* pref_p = (int*)alloc(1024 * 4);
  int* pref_n = (int*)alloc(1024 * 4);
  int* srt_p = (int*)alloc((size_t)E * 4);
  int* srt_n = (int*)alloc((size_t)E * 4);
  unsigned short* xb16 = (unsigned short*)alloc((size_t)N * 128 * 2);
  unsigned short* w0f = (unsigned short*)alloc(65536 * 2);
  unsigned short* w1f = (unsigned short*)alloc(32768 * 2);
  unsigned short* h0b = (unsigned short*)alloc((size_t)N * 512 * 2);
  float* as0p = (float*)alloc((size_t)N * 4 * 4);
  float* ad0p = (float*)alloc((size_t)N * 4 * 4);
  float* as0n = (float*)alloc((size_t)N * 4 * 4);
  float* ad0n = (float*)alloc((size_t)N * 4 * 4);
  float* as1p = (float*)alloc((size_t)N * 4);
  float* ad1p = (float*)alloc((size_t)N * 4);
  float* as1n = (float*)alloc((size_t)N * 4);
  float* ad1n = (float*)alloc((size_t)N * 4);
  float* inv0p = (float*)alloc((size_t)N * 4 * 4);
  float* wslf0p = (float*)alloc((size_t)N * 4 * 4);
  float* inv0n = (float*)alloc((size_t)N * 4 * 4);
  float* wslf0n = (float*)alloc((size_t)N * 4 * 4);
  float* inv1p = (float*)alloc((size_t)N * 4);
  float* wslf1p = (float*)alloc((size_t)N * 4);
  float* inv1n = (float*)alloc((size_t)N * 4);
  float* wslf1n = (float*)alloc((size_t)N * 4);
  float* alpha0p = (float*)alloc((size_t)E * 4 * 4);
  float* alpha0n = (float*)alloc((size_t)E * 4 * 4);
  float* alpha1p = (float*)alloc((size_t)E * 4);
  float* alpha1n = (float*)alloc((size_t)E * 4);
  unsigned short* xbufb = (unsigned short*)alloc((size_t)N * 256 * 2);
  float* h1 = (float*)alloc((size_t)N * 128 * 4);

  hipMemsetAsync(base, 0, cntBytes, stream);

  int egrid = (E + 255) / 256;
  int nb = (N + 1023) / 1024;  // 49
  k_hist2<<<2 * egrid, 256, 0, stream>>>(ep, en, cnt_p, cnt_n, E, egrid);
  k_scan_partial2<<<2 * nb, 256, 0, stream>>>(cnt_p, cnt_n, part_p, part_n, N, nb);
  k_scan_top2<<<2, 64, 0, stream>>>(part_p, part_n, pref_p, pref_n, nb, off_p + N, off_n + N, E);
  k_scan_final2<<<2 * nb, 256, 0, stream>>>(cnt_p, cnt_n, pref_p, pref_n, off_p, off_n, N, nb);
  k_scatter2<<<2 * egrid, 256, 0, stream>>>(ep, en, off_p, off_n, cnt_p, cnt_n, srt_p, srt_n, E, egrid);

  k_prep<<<3173, 256, 0, stream>>>(x, W0p, W0n, W1p, W1n, xb16, w0f, w1f);

  int ngrid = (N + 3) / 4;

  // layer 0: waves = 1 row-group x 4 col-groups; grid-y 2 -> A HBM traffic 2 passes
  dim3 g0((N + 31) / 32, 2);
  k_mgemm<4, 1, 4, 512, 1, 4><<<g0, 256, 0, stream>>>(xb16, w0f, h0b, (float*)nullptr, N,
                                                      asrc0p, adst0p, asrc0n, adst0n,
                                                      as0p, ad0p, as0n, ad0n);
  k_sa0<<<ngrid, 256, 0, stream>>>(as0p, ad0p, off_p, srt_p, alpha0p, inv0p, wslf0p,
                                   as0n, ad0n, off_n, srt_n, alpha0n, inv0n, wslf0n, N);
  k_gather0<<<ngrid, 256, 0, stream>>>(h0b, off_p, srt_p, alpha0p, inv0p, wslf0p,
                                       off_n, srt_n, alpha0n, inv0n, wslf0n, b0p, b0n, xbufb, N);

  // layer 1: waves = 2 row-groups x 2 col-groups; single y-block -> A read once
  dim3 g1((N + 63) / 64, 1);
  k_mgemm<8, 0, 1, 128, 2, 2><<<g1, 256, 0, stream>>>(xbufb, w1f, (unsigned short*)nullptr, h1, N,
                                                      asrc1p, adst1p, asrc1n, adst1n,
                                                      as1p, ad1p, as1n, ad1n);
  k_sa1<<<ngrid, 256, 0, stream>>>(as1p, ad1p, off_p, srt_p, alpha1p, inv1p, wslf1p,
                                   as1n, ad1n, off_n, srt_n, alpha1n, inv1n, wslf1n, N);
  k_gather1<<<ngrid, 256, 0, stream>>>(h1, off_p, srt_p, alpha1p, inv1p, wslf1p,
                                       off_n, srt_n, alpha1n, inv1n, wslf1n, b1p, b1n, (float*)d_out, N);
}

// Round 10
// 543.969 us; speedup vs baseline: 1.5580x; 1.0575x over previous
//
#include <hip/hip_runtime.h>
#include <cstdint>

#define N_NODES 50000
#define N_EDGES 800000

typedef __attribute__((ext_vector_type(8))) short bf16x8;
typedef __attribute__((ext_vector_type(4))) float f32x4;

__device__ __forceinline__ float lrelu(float x) { return x >= 0.f ? x : 0.2f * x; }

__device__ __forceinline__ unsigned short f2b(float f) {  // fp32 -> bf16 RNE
  unsigned int u = __float_as_uint(f);
  u += 0x7FFFu + ((u >> 16) & 1u);
  return (unsigned short)(u >> 16);
}
__device__ __forceinline__ float blo(unsigned int u) { return __uint_as_float(u << 16); }
__device__ __forceinline__ float bhi(unsigned int u) { return __uint_as_float(u & 0xFFFF0000u); }

// ---------------- CSR build (pos+neg merged per kernel) ----------------

__global__ __launch_bounds__(256) void k_hist2(const int* __restrict__ ep, const int* __restrict__ en,
                                               int* __restrict__ cntP, int* __restrict__ cntN, int E, int half) {
  int b = blockIdx.x;
  const int* ei = (b < half) ? ep : en;
  int* cnt = (b < half) ? cntP : cntN;
  int e = (b % half) * 256 + threadIdx.x;
  if (e < E) atomicAdd(&cnt[ei[E + e]], 1);
}

__global__ __launch_bounds__(256) void k_scan_partial2(const int* __restrict__ cntP, const int* __restrict__ cntN,
                                                       int* __restrict__ partP, int* __restrict__ partN,
                                                       int N, int half) {
  int b = blockIdx.x;
  const int* cnt = (b < half) ? cntP : cntN;
  int* partial = (b < half) ? partP : partN;
  int bb = b % half;
  int t = threadIdx.x;
  int sum = 0;
#pragma unroll
  for (int i = 0; i < 4; i++) {
    int idx = bb * 1024 + i * 256 + t;
    if (idx < N) sum += cnt[idx];
  }
#pragma unroll
  for (int o = 32; o; o >>= 1) sum += __shfl_xor(sum, o);
  __shared__ int sh[4];
  if ((t & 63) == 0) sh[t >> 6] = sum;
  __syncthreads();
  if (t == 0) partial[bb] = sh[0] + sh[1] + sh[2] + sh[3];
}

__global__ __launch_bounds__(64) void k_scan_top2(const int* __restrict__ partP, const int* __restrict__ partN,
                                                  int* __restrict__ prefP, int* __restrict__ prefN,
                                                  int nb, int* __restrict__ offPN, int* __restrict__ offNN, int total) {
  const int* partial = (blockIdx.x == 0) ? partP : partN;
  int* pref = (blockIdx.x == 0) ? prefP : prefN;
  int* offN = (blockIdx.x == 0) ? offPN : offNN;
  int l = threadIdx.x;
  int v = (l < nb) ? partial[l] : 0;
  int x = v;
#pragma unroll
  for (int o = 1; o < 64; o <<= 1) {
    int y = __shfl_up(x, o);
    if (l >= o) x += y;
  }
  if (l < nb) pref[l] = x - v;  // exclusive
  if (l == 0) *offN = total;
}

__global__ __launch_bounds__(256) void k_scan_final2(const int* __restrict__ cntP, const int* __restrict__ cntN,
                                                     const int* __restrict__ prefP, const int* __restrict__ prefN,
                                                     int* __restrict__ offP, int* __restrict__ offN,
                                                     int N, int half) {
  int b = blockIdx.x;
  const int* cnt = (b < half) ? cntP : cntN;
  const int* pref = (b < half) ? prefP : prefN;
  int* off = (b < half) ? offP : offN;
  int bb = b % half;
  int t = threadIdx.x;
  int idx0 = bb * 1024 + t * 4;
  int v0 = (idx0 + 0 < N) ? cnt[idx0 + 0] : 0;
  int v1 = (idx0 + 1 < N) ? cnt[idx0 + 1] : 0;
  int v2 = (idx0 + 2 < N) ? cnt[idx0 + 2] : 0;
  int v3 = (idx0 + 3 < N) ? cnt[idx0 + 3] : 0;
  int s = v0 + v1 + v2 + v3;
  int lane = t & 63, w = t >> 6;
  int x = s;
#pragma unroll
  for (int o = 1; o < 64; o <<= 1) {
    int y = __shfl_up(x, o);
    if (lane >= o) x += y;
  }
  __shared__ int wtot[4];
  if (lane == 63) wtot[w] = x;
  __syncthreads();
  int woff = 0;
#pragma unroll
  for (int i = 0; i < 4; i++)
    if (i < w) woff += wtot[i];
  int excl = pref[bb] + woff + (x - s);
  if (idx0 + 0 < N) off[idx0 + 0] = excl;
  excl += v0;
  if (idx0 + 1 < N) off[idx0 + 1] = excl;
  excl += v1;
  if (idx0 + 2 < N) off[idx0 + 2] = excl;
  excl += v2;
  if (idx0 + 3 < N) off[idx0 + 3] = excl;
}

__global__ __launch_bounds__(256) void k_scatter2(const int* __restrict__ ep, const int* __restrict__ en,
                                                  const int* __restrict__ offP, const int* __restrict__ offN,
                                                  int* __restrict__ cntP, int* __restrict__ cntN,
                                                  int* __restrict__ srtP, int* __restrict__ srtN, int E, int half) {
  int b = blockIdx.x;
  const int* ei = (b < half) ? ep : en;
  const int* off = (b < half) ? offP : offN;
  int* cnt = (b < half) ? cntP : cntN;
  int* srt = (b < half) ? srtP : srtN;
  int e = (b % half) * 256 + threadIdx.x;
  if (e < E) {
    int s = ei[e], d = ei[E + e];
    int p = atomicSub(&cnt[d], 1) - 1;  // reuses histogram, ends at zero
    srt[off[d] + p] = s;
  }
}

// ---------------- prep: x -> bf16, W -> fragment-order bf16 ----------------

__global__ __launch_bounds__(256) void k_prep(const float* __restrict__ x,
                                              const float* __restrict__ W0p, const float* __restrict__ W0n,
                                              const float* __restrict__ W1p, const float* __restrict__ W1n,
                                              unsigned short* __restrict__ xb,
                                              unsigned short* __restrict__ w0f,
                                              unsigned short* __restrict__ w1f) {
  int b = blockIdx.x, t = threadIdx.x;
  if (b < 3125) {
    int base = (b * 256 + t) * 8;
    float4 v0 = *(const float4*)&x[base];
    float4 v1 = *(const float4*)&x[base + 4];
    ushort4 a, c;
    a.x = f2b(v0.x); a.y = f2b(v0.y); a.z = f2b(v0.z); a.w = f2b(v0.w);
    c.x = f2b(v1.x); c.y = f2b(v1.y); c.z = f2b(v1.z); c.w = f2b(v1.w);
    *(ushort4*)&xb[base] = a;
    *(ushort4*)&xb[base + 4] = c;
  } else if (b < 3157) {
    int tid = (b - 3125) * 256 + t;  // 0..8191
    int lane = tid & 63;
    int rest = tid >> 6;
    int ks = rest & 3; rest >>= 2;
    int n = rest & 3;
    int g = rest >> 2;  // 0..7
    int col = (g & 3) * 64 + n * 16 + (lane & 15);
    const float* W = (g < 4) ? W0p : W0n;
    size_t dst = ((((size_t)(g * 4 + n)) * 4 + ks) * 64 + lane) * 8;
#pragma unroll
    for (int j = 0; j < 8; j++) {
      int k = ks * 32 + (lane >> 4) * 8 + j;
      w0f[dst + j] = f2b(W[k * 256 + col]);
    }
  } else {
    int tid = (b - 3157) * 256 + t;  // 0..4095
    int lane = tid & 63;
    int rest = tid >> 6;
    int ks = rest & 7; rest >>= 3;
    int n = rest & 3;
    int g = rest >> 2;  // 0..1
    int col = n * 16 + (lane & 15);
    const float* W = g ? W1n : W1p;
    size_t dst = ((((size_t)(g * 4 + n)) * 8 + ks) * 64 + lane) * 8;
#pragma unroll
    for (int j = 0; j < 8; j++) {
      int k = ks * 32 + (lane >> 4) * 8 + j;
      w1f[dst + j] = f2b(W[k * 64 + col]);
    }
  }
}

// ---------------- MFMA GEMM: C[N x NC] = Abf16[N x K] @ Bfrag, + att dots ----------------
// Waves arranged (WROWS x WCOLS): wave handles 32 rows x one 64-col group.
// Col-groups within a block share A rows through L1 (A HBM traffic = gridDim.y passes).

template <int KSTEPS, int CBF16, int H, int NC, int WROWS, int WCOLS>
__global__ __launch_bounds__(256) void k_mgemm(const unsigned short* __restrict__ Ab,
                                               const unsigned short* __restrict__ Bf,
                                               unsigned short* __restrict__ Cb, float* __restrict__ Cf,
                                               int Nrows,
                                               const float* __restrict__ attSP, const float* __restrict__ attDP,
                                               const float* __restrict__ attSN, const float* __restrict__ attDN,
                                               float* __restrict__ oSP, float* __restrict__ oDP,
                                               float* __restrict__ oSN, float* __restrict__ oDN) {
  constexpr int K = KSTEPS * 32;
  int w = threadIdx.x >> 6, lane = threadIdx.x & 63;
  int wr = w / WCOLS, wc = w % WCOLS;
  int row0 = blockIdx.x * (WROWS * 32) + wr * 32;
  int g = blockIdx.y * WCOLS + wc;
  const bf16x8* Bv = (const bf16x8*)Bf;
  const bf16x8* Av = (const bf16x8*)Ab;  // row stride K/8 vecs

  f32x4 acc[2][4];
#pragma unroll
  for (int mi = 0; mi < 2; mi++)
#pragma unroll
    for (int n = 0; n < 4; n++) acc[mi][n] = (f32x4){0.f, 0.f, 0.f, 0.f};

  int r0 = row0 + (lane & 15);
  int r1 = r0 + 16;
  bool v0 = r0 < Nrows, v1 = r1 < Nrows;
  size_t arow0 = (size_t)r0 * (K / 8) + (lane >> 4);
  size_t arow1 = (size_t)r1 * (K / 8) + (lane >> 4);
  const bf16x8 az = {0, 0, 0, 0, 0, 0, 0, 0};

  for (int kh = 0; kh < KSTEPS / 4; kh++) {
#pragma unroll
    for (int k4 = 0; k4 < 4; k4++) {
      int ks = kh * 4 + k4;
      bf16x8 a0 = v0 ? Av[arow0 + ks * 4] : az;
      bf16x8 a1 = v1 ? Av[arow1 + ks * 4] : az;
      bf16x8 b0 = Bv[((size_t)(g * 4 + 0) * KSTEPS + ks) * 64 + lane];
      bf16x8 b1 = Bv[((size_t)(g * 4 + 1) * KSTEPS + ks) * 64 + lane];
      bf16x8 b2 = Bv[((size_t)(g * 4 + 2) * KSTEPS + ks) * 64 + lane];
      bf16x8 b3 = Bv[((size_t)(g * 4 + 3) * KSTEPS + ks) * 64 + lane];
      acc[0][0] = __builtin_amdgcn_mfma_f32_16x16x32_bf16(a0, b0, acc[0][0], 0, 0, 0);
      acc[0][1] = __builtin_amdgcn_mfma_f32_16x16x32_bf16(a0, b1, acc[0][1], 0, 0, 0);
      acc[0][2] = __builtin_amdgcn_mfma_f32_16x16x32_bf16(a0, b2, acc[0][2], 0, 0, 0);
      acc[0][3] = __builtin_amdgcn_mfma_f32_16x16x32_bf16(a0, b3, acc[0][3], 0, 0, 0);
      acc[1][0] = __builtin_amdgcn_mfma_f32_16x16x32_bf16(a1, b0, acc[1][0], 0, 0, 0);
      acc[1][1] = __builtin_amdgcn_mfma_f32_16x16x32_bf16(a1, b1, acc[1][1], 0, 0, 0);
      acc[1][2] = __builtin_amdgcn_mfma_f32_16x16x32_bf16(a1, b2, acc[1][2], 0, 0, 0);
      acc[1][3] = __builtin_amdgcn_mfma_f32_16x16x32_bf16(a1, b3, acc[1][3], 0, 0, 0);
    }
  }

  // C store (C/D layout m89: col=lane&15, row=(lane>>4)*4+reg)
#pragma unroll
  for (int mi = 0; mi < 2; mi++)
#pragma unroll
    for (int n = 0; n < 4; n++)
#pragma unroll
      for (int reg = 0; reg < 4; reg++) {
        int row = row0 + mi * 16 + (lane >> 4) * 4 + reg;
        int col = g * 64 + n * 16 + (lane & 15);
        if (row < Nrows) {
          if (CBF16)
            Cb[(size_t)row * NC + col] = f2b(acc[mi][n][reg]);
          else
            Cf[(size_t)row * NC + col] = acc[mi][n][reg];
        }
      }

  // att dots
  constexpr int POSG = NC / 128;  // pos col-groups
  int isNeg = (g >= POSG) ? 1 : 0;
  int head = isNeg ? g - POSG : g;
  const float* wS = (isNeg ? attSN : attSP) + head * 64;
  const float* wD = (isNeg ? attDN : attDP) + head * 64;
  float* oS = isNeg ? oSN : oSP;
  float* oD = isNeg ? oDN : oDP;
  float ws0 = wS[0 * 16 + (lane & 15)], ws1 = wS[1 * 16 + (lane & 15)];
  float ws2 = wS[2 * 16 + (lane & 15)], ws3 = wS[3 * 16 + (lane & 15)];
  float wd0 = wD[0 * 16 + (lane & 15)], wd1 = wD[1 * 16 + (lane & 15)];
  float wd2 = wD[2 * 16 + (lane & 15)], wd3 = wD[3 * 16 + (lane & 15)];
#pragma unroll
  for (int mi = 0; mi < 2; mi++)
#pragma unroll
    for (int reg = 0; reg < 4; reg++) {
      float ps = acc[mi][0][reg] * ws0 + acc[mi][1][reg] * ws1 + acc[mi][2][reg] * ws2 + acc[mi][3][reg] * ws3;
      float pd = acc[mi][0][reg] * wd0 + acc[mi][1][reg] * wd1 + acc[mi][2][reg] * wd2 + acc[mi][3][reg] * wd3;
#pragma unroll
      for (int o = 1; o < 16; o <<= 1) {
        ps += __shfl_xor(ps, o);
        pd += __shfl_xor(pd, o);
      }
      int row = row0 + mi * 16 + (lane >> 4) * 4 + reg;
      if ((lane & 15) == 0 && row < Nrows) {
        oS[(size_t)row * H + head] = ps;
        oD[(size_t)row * H + head] = pd;
      }
    }
}

// ---------------- k_sa0: per-edge raw exp weights (no-max softmax) + per-node inv/self ----------------

__global__ __launch_bounds__(256) void k_sa0(const float* __restrict__ asP, const float* __restrict__ adP,
                                             const int* __restrict__ offP, const int* __restrict__ srtP,
                                             float* __restrict__ alphaP, float* __restrict__ invP,
                                             float* __restrict__ wslfP,
                                             const float* __restrict__ asN, const float* __restrict__ adN,
                                             const int* __restrict__ offN, const int* __restrict__ srtN,
                                             float* __restrict__ alphaN, float* __restrict__ invN,
                                             float* __restrict__ wslfN, int N) {
  int n = blockIdx.x * 4 + (threadIdx.x >> 6);
  if (n >= N) return;
  int l = threadIdx.x & 63;
  {
    int base = offP[n], deg = offP[n + 1] - base;
    float4 ad4 = *(const float4*)&adP[(size_t)n * 4];
    float s0 = 0.f, s1 = 0.f, s2 = 0.f, s3 = 0.f;
    for (int i = l; i < deg; i += 64) {
      int s = srtP[base + i];
      float4 av = *(const float4*)&asP[(size_t)s * 4];
      float4 ex;
      ex.x = __expf(lrelu(av.x + ad4.x));
      ex.y = __expf(lrelu(av.y + ad4.y));
      ex.z = __expf(lrelu(av.z + ad4.z));
      ex.w = __expf(lrelu(av.w + ad4.w));
      *(float4*)&alphaP[(size_t)(base + i) * 4] = ex;
      s0 += ex.x; s1 += ex.y; s2 += ex.z; s3 += ex.w;
    }
#pragma unroll
    for (int o = 32; o; o >>= 1) {
      s0 += __shfl_xor(s0, o);
      s1 += __shfl_xor(s1, o);
      s2 += __shfl_xor(s2, o);
      s3 += __shfl_xor(s3, o);
    }
    if (l == 0) {
      float4 as4 = *(const float4*)&asP[(size_t)n * 4];
      float e0 = __expf(lrelu(as4.x + ad4.x));
      float e1 = __expf(lrelu(as4.y + ad4.y));
      float e2 = __expf(lrelu(as4.z + ad4.z));
      float e3 = __expf(lrelu(as4.w + ad4.w));
      float i0 = 1.f / (s0 + e0 + 1e-16f);
      float i1 = 1.f / (s1 + e1 + 1e-16f);
      float i2 = 1.f / (s2 + e2 + 1e-16f);
      float i3 = 1.f / (s3 + e3 + 1e-16f);
      *(float4*)&invP[(size_t)n * 4] = make_float4(i0, i1, i2, i3);
      *(float4*)&wslfP[(size_t)n * 4] = make_float4(e0 * i0, e1 * i1, e2 * i2, e3 * i3);
    }
  }
  {
    int base = offN[n], deg = offN[n + 1] - base;
    float4 ad4 = *(const float4*)&adN[(size_t)n * 4];
    float s0 = 0.f, s1 = 0.f, s2 = 0.f, s3 = 0.f;
    for (int i = l; i < deg; i += 64) {
      int s = srtN[base + i];
      float4 av = *(const float4*)&asN[(size_t)s * 4];
      float4 ex;
      ex.x = __expf(lrelu(av.x + ad4.x));
      ex.y = __expf(lrelu(av.y + ad4.y));
      ex.z = __expf(lrelu(av.z + ad4.z));
      ex.w = __expf(lrelu(av.w + ad4.w));
      *(float4*)&alphaN[(size_t)(base + i) * 4] = ex;
      s0 += ex.x; s1 += ex.y; s2 += ex.z; s3 += ex.w;
    }
#pragma unroll
    for (int o = 32; o; o >>= 1) {
      s0 += __shfl_xor(s0, o);
      s1 += __shfl_xor(s1, o);
      s2 += __shfl_xor(s2, o);
      s3 += __shfl_xor(s3, o);
    }
    if (l == 0) {
      float4 as4 = *(const float4*)&asN[(size_t)n * 4];
      float e0 = __expf(lrelu(as4.x + ad4.x));
      float e1 = __expf(lrelu(as4.y + ad4.y));
      float e2 = __expf(lrelu(as4.z + ad4.z));
      float e3 = __expf(lrelu(as4.w + ad4.w));
      float i0 = 1.f / (s0 + e0 + 1e-16f);
      float i1 = 1.f / (s1 + e1 + 1e-16f);
      float i2 = 1.f / (s2 + e2 + 1e-16f);
      float i3 = 1.f / (s3 + e3 + 1e-16f);
      *(float4*)&invN[(size_t)n * 4] = make_float4(i0, i1, i2, i3);
      *(float4*)&wslfN[(size_t)n * 4] = make_float4(e0 * i0, e1 * i1, e2 * i2, e3 * i3);
    }
  }
}

// ---------------- layer-0 gather: round-7 structure (separate P/N loops, 8-deep) ----------------

__device__ __forceinline__ float4 gather0b(const unsigned short* __restrict__ h0b, int colElem,
                                           const float* __restrict__ alpha, int hl,
                                           const int* __restrict__ srt, int base, int deg) {
  float4 acc = make_float4(0.f, 0.f, 0.f, 0.f);
  for (int j = 0; j < deg; j += 8) {
    int idx[8];
    float w[8];
#pragma unroll
    for (int s2 = 0; s2 < 8; s2++) {
      int jj = j + s2;
      bool v = jj < deg;
      int p = v ? base + jj : 0;  // pos 0 always valid; weight 0 kills contribution
      idx[s2] = srt[p];
      w[s2] = v ? alpha[(size_t)p * 4 + hl] : 0.f;
    }
#pragma unroll
    for (int s2 = 0; s2 < 8; s2++) {
      uint2 hv = *(const uint2*)&h0b[(size_t)idx[s2] * 512 + colElem];
      acc.x = fmaf(w[s2], blo(hv.x), acc.x);
      acc.y = fmaf(w[s2], bhi(hv.x), acc.y);
      acc.z = fmaf(w[s2], blo(hv.y), acc.z);
      acc.w = fmaf(w[s2], bhi(hv.y), acc.w);
    }
  }
  return acc;
}

__global__ __launch_bounds__(256) void k_gather0(const unsigned short* __restrict__ h0b,
                                                 const int* __restrict__ offP, const int* __restrict__ srtP,
                                                 const float* __restrict__ alphaP, const float* __restrict__ invP,
                                                 const float* __restrict__ wslfP,
                                                 const int* __restrict__ offN, const int* __restrict__ srtN,
                                                 const float* __restrict__ alphaN, const float* __restrict__ invN,
                                                 const float* __restrict__ wslfN,
                                                 const float* __restrict__ bP, const float* __restrict__ bN,
                                                 unsigned short* __restrict__ xb, int N) {
  int n = blockIdx.x * 4 + (threadIdx.x >> 6);
  if (n >= N) return;
  int l = threadIdx.x & 63;
  int hl = l >> 4;

  int baseP = offP[n], degP = offP[n + 1] - baseP;
  float4 accP = gather0b(h0b, l * 4, alphaP, hl, srtP, baseP, degP);
  {
    float iv = invP[(size_t)n * 4 + hl];
    float ws = wslfP[(size_t)n * 4 + hl];
    uint2 hs = *(const uint2*)&h0b[(size_t)n * 512 + l * 4];
    accP.x = fmaf(accP.x, iv, ws * blo(hs.x));
    accP.y = fmaf(accP.y, iv, ws * bhi(hs.x));
    accP.z = fmaf(accP.z, iv, ws * blo(hs.y));
    accP.w = fmaf(accP.w, iv, ws * bhi(hs.y));
  }

  int baseN = offN[n], degN = offN[n + 1] - baseN;
  float4 accN = gather0b(h0b, 256 + l * 4, alphaN, hl, srtN, baseN, degN);
  {
    float iv = invN[(size_t)n * 4 + hl];
    float ws = wslfN[(size_t)n * 4 + hl];
    uint2 hs = *(const uint2*)&h0b[(size_t)n * 512 + 256 + l * 4];
    accN.x = fmaf(accN.x, iv, ws * blo(hs.x));
    accN.y = fmaf(accN.y, iv, ws * bhi(hs.x));
    accN.z = fmaf(accN.z, iv, ws * blo(hs.y));
    accN.w = fmaf(accN.w, iv, ws * bhi(hs.y));
  }

  float4 bp = *(const float4*)&bP[l * 4];
  float4 bn = *(const float4*)&bN[l * 4];
  float rx = accP.x + bp.x - accN.x - bn.x;
  float ry = accP.y + bp.y - accN.y - bn.y;
  float rz = accP.z + bp.z - accN.z - bn.z;
  float rw = accP.w + bp.w - accN.w - bn.w;
  rx = rx > 0.f ? rx : expm1f(rx);
  ry = ry > 0.f ? ry : expm1f(ry);
  rz = rz > 0.f ? rz : expm1f(rz);
  rw = rw > 0.f ? rw : expm1f(rw);
  ushort4 r;
  r.x = f2b(rx); r.y = f2b(ry); r.z = f2b(rz); r.w = f2b(rw);
  *(ushort4*)&xb[(size_t)n * 256 + l * 4] = r;
}

// ---------------- k_sa1 / k_gather1 (1 head), bf16 h1, split-wave P/N ----------------

__global__ __launch_bounds__(256) void k_sa1(const float* __restrict__ asP, const float* __restrict__ adP,
                                             const int* __restrict__ offP, const int* __restrict__ srtP,
                                             float* __restrict__ alphaP, float* __restrict__ invP,
                                             float* __restrict__ wslfP,
                                             const float* __restrict__ asN, const float* __restrict__ adN,
                                             const int* __restrict__ offN, const int* __restrict__ srtN,
                                             float* __restrict__ alphaN, float* __restrict__ invN,
                                             float* __restrict__ wslfN, int N) {
  int n = blockIdx.x * 4 + (threadIdx.x >> 6);
  if (n >= N) return;
  int l = threadIdx.x & 63;
  {
    int base = offP[n], deg = offP[n + 1] - base;
    float ad = adP[n];
    float s = 0.f;
    for (int i = l; i < deg; i += 64) {
      float ex = __expf(lrelu(asP[srtP[base + i]] + ad));
      alphaP[base + i] = ex;
      s += ex;
    }
#pragma unroll
    for (int o = 32; o; o >>= 1) s += __shfl_xor(s, o);
    if (l == 0) {
      float se = __expf(lrelu(asP[n] + ad));
      float iv = 1.f / (s + se + 1e-16f);
      invP[n] = iv;
      wslfP[n] = se * iv;
    }
  }
  {
    int base = offN[n], deg = offN[n + 1] - base;
    float ad = adN[n];
    float s = 0.f;
    for (int i = l; i < deg; i += 64) {
      float ex = __expf(lrelu(asN[srtN[base + i]] + ad));
      alphaN[base + i] = ex;
      s += ex;
    }
#pragma unroll
    for (int o = 32; o; o >>= 1) s += __shfl_xor(s, o);
    if (l == 0) {
      float se = __expf(lrelu(asN[n] + ad));
      float iv = 1.f / (s + se + 1e-16f);
      invN[n] = iv;
      wslfN[n] = se * iv;
    }
  }
}

// lanes 0-31: pos half (ch 2*lh, 2*lh+1); lanes 32-63: neg half. One uint (2 bf16) per lane
// per row; both signs' rows in flight concurrently; P-N combine via one shfl pair.
__global__ __launch_bounds__(256) void k_gather1(const unsigned short* __restrict__ h1b,
                                                 const int* __restrict__ offP, const int* __restrict__ srtP,
                                                 const float* __restrict__ alphaP, const float* __restrict__ invP,
                                                 const float* __restrict__ wslfP,
                                                 const int* __restrict__ offN, const int* __restrict__ srtN,
                                                 const float* __restrict__ alphaN, const float* __restrict__ invN,
                                                 const float* __restrict__ wslfN,
                                                 const float* __restrict__ bP, const float* __restrict__ bN,
                                                 float* __restrict__ out, int N) {
  int n = blockIdx.x * 4 + (threadIdx.x >> 6);
  if (n >= N) return;
  int l = threadIdx.x & 63;
  int half = l >> 5;  // 0: pos, 1: neg
  int lh = l & 31;
  const int* off = half ? offN : offP;
  const int* srt = half ? srtN : srtP;
  const float* alpha = half ? alphaN : alphaP;
  const float* inv = half ? invN : invP;
  const float* wslf = half ? wslfN : wslfP;
  int base = off[n], deg = off[n + 1] - base;
  int colB = half * 64 + lh * 2;  // bf16 element index within the 128-elem row

  float ax = 0.f, ay = 0.f;
  for (int j = 0; j < deg; j += 8) {
    int idx[8];
    float w[8];
#pragma unroll
    for (int s = 0; s < 8; s++) {
      int jj = j + s;
      bool v = jj < deg;
      int p = v ? base + jj : 0;
      idx[s] = srt[p];
      w[s] = v ? alpha[p] : 0.f;
    }
#pragma unroll
    for (int s = 0; s < 8; s++) {
      unsigned int hv = *(const unsigned int*)&h1b[(size_t)idx[s] * 128 + colB];
      ax = fmaf(w[s], blo(hv), ax);
      ay = fmaf(w[s], bhi(hv), ay);
    }
  }
  {
    float iv = inv[n], ws = wslf[n];
    unsigned int hs = *(const unsigned int*)&h1b[(size_t)n * 128 + colB];
    ax = fmaf(ax, iv, ws * blo(hs));
    ay = fmaf(ay, iv, ws * bhi(hs));
  }
  float nx = __shfl(ax, l + 32);  // for l<32: neg-half acc from lane l+32
  float ny = __shfl(ay, l + 32);
  if (l < 32) {
    int c = lh * 2;
    float2 r;
    r.x = (ax + bP[c]) - (nx + bN[c]);
    r.y = (ay + bP[c + 1]) - (ny + bN[c + 1]);
    *(float2*)&out[(size_t)n * 64 + c] = r;
  }
}

// ---------------- launch ----------------

extern "C" void kernel_launch(void* const* d_in, const int* in_sizes, int n_in,
                              void* d_out, int out_size, void* d_ws, size_t ws_size,
                              hipStream_t stream) {
  const float* x = (const float*)d_in[0];
  const int* ep = (const int*)d_in[1];
  const int* en = (const int*)d_in[2];
  const float* W0p = (const float*)d_in[3];
  const float* asrc0p = (const float*)d_in[4];
  const float* adst0p = (const float*)d_in[5];
  const float* b0p = (const float*)d_in[6];
  const float* W0n = (const float*)d_in[7];
  const float* asrc0n = (const float*)d_in[8];
  const float* adst0n = (const float*)d_in[9];
  const float* b0n = (const float*)d_in[10];
  const float* W1p = (const float*)d_in[11];
  const float* asrc1p = (const float*)d_in[12];
  const float* adst1p = (const float*)d_in[13];
  const float* b1p = (const float*)d_in[14];
  const float* W1n = (const float*)d_in[15];
  const float* asrc1n = (const float*)d_in[16];
  const float* adst1n = (const float*)d_in[17];
  const float* b1n = (const float*)d_in[18];

  const int N = N_NODES, E = N_EDGES;
  char* base = (char*)d_ws;
  size_t o = 0;
  auto alloc = [&](size_t bytes) -> void* {
    void* r = base + o;
    o = (o + bytes + 255) & ~(size_t)255;
    return r;
  };
  int* cnt_p = (int*)alloc((size_t)N * 4);
  int* cnt_n = (int*)alloc((size_t)N * 4);
  size_t cntBytes = o;  // memset covers both count arrays (+padding)
  int* off_p = (int*)alloc((size_t)(N + 1) * 4);
  int* off_n = (int*)alloc((size_t)(N + 1) * 4);
  int* part_p = (int*)alloc(1024 * 4);
  int* part_n = (int*)alloc(1024 * 4);
  int* pref_p = (int*)alloc(1024 * 4);
  int* pref_n = (int*)alloc(1024 * 4);
  int* srt_p = (int*)alloc((size_t)E * 4);
  int* srt_n = (int*)alloc((size_t)E * 4);
  unsigned short* xb16 = (unsigned short*)alloc((size_t)N * 128 * 2);
  unsigned short* w0f = (unsigned short*)alloc(65536 * 2);
  unsigned short* w1f = (unsigned short*)alloc(32768 * 2);
  unsigned short* h0b = (unsigned short*)alloc((size_t)N * 512 * 2);
  float* as0p = (float*)alloc((size_t)N * 4 * 4);
  float* ad0p = (float*)alloc((size_t)N * 4 * 4);
  float* as0n = (float*)alloc((size_t)N * 4 * 4);
  float* ad0n = (float*)alloc((size_t)N * 4 * 4);
  float* as1p = (float*)alloc((size_t)N * 4);
  float* ad1p = (float*)alloc((size_t)N * 4);
  float* as1n = (float*)alloc((size_t)N * 4);
  float* ad1n = (float*)alloc((size_t)N * 4);
  float* inv0p = (float*)alloc((size_t)N * 4 * 4);
  float* wslf0p = (float*)alloc((size_t)N * 4 * 4);
  float* inv0n = (float*)alloc((size_t)N * 4 * 4);
  float* wslf0n = (float*)alloc((size_t)N * 4 * 4);
  float* inv1p = (float*)alloc((size_t)N * 4);
  float* wslf1p = (float*)alloc((size_t)N * 4);
  float* inv1n = (float*)alloc((size_t)N * 4);
  float* wslf1n = (float*)alloc((size_t)N * 4);
  float* alpha0p = (float*)alloc((size_t)E * 4 * 4);
  float* alpha0n = (float*)alloc((size_t)E * 4 * 4);
  float* alpha1p = (float*)alloc((size_t)E * 4);
  float* alpha1n = (float*)alloc((size_t)E * 4);
  unsigned short* xbufb = (unsigned short*)alloc((size_t)N * 256 * 2);
  unsigned short* h1b = (unsigned short*)alloc((size_t)N * 128 * 2);

  hipMemsetAsync(base, 0, cntBytes, stream);

  int egrid = (E + 255) / 256;
  int nb = (N + 1023) / 1024;  // 49
  k_hist2<<<2 * egrid, 256, 0, stream>>>(ep, en, cnt_p, cnt_n, E, egrid);
  k_scan_partial2<<<2 * nb, 256, 0, stream>>>(cnt_p, cnt_n, part_p, part_n, N, nb);
  k_scan_top2<<<2, 64, 0, stream>>>(part_p, part_n, pref_p, pref_n, nb, off_p + N, off_n + N, E);
  k_scan_final2<<<2 * nb, 256, 0, stream>>>(cnt_p, cnt_n, pref_p, pref_n, off_p, off_n, N, nb);
  k_scatter2<<<2 * egrid, 256, 0, stream>>>(ep, en, off_p, off_n, cnt_p, cnt_n, srt_p, srt_n, E, egrid);

  k_prep<<<3173, 256, 0, stream>>>(x, W0p, W0n, W1p, W1n, xb16, w0f, w1f);

  int ngrid = (N + 3) / 4;

  // layer 0: waves = 1 row-group x 4 col-groups; grid-y 2 -> A HBM traffic 2 passes
  dim3 g0((N + 31) / 32, 2);
  k_mgemm<4, 1, 4, 512, 1, 4><<<g0, 256, 0, stream>>>(xb16, w0f, h0b, (float*)nullptr, N,
                                                      asrc0p, adst0p, asrc0n, adst0n,
                                                      as0p, ad0p, as0n, ad0n);
  k_sa0<<<ngrid, 256, 0, stream>>>(as0p, ad0p, off_p, srt_p, alpha0p, inv0p, wslf0p,
                                   as0n, ad0n, off_n, srt_n, alpha0n, inv0n, wslf0n, N);
  k_gather0<<<ngrid, 256, 0, stream>>>(h0b, off_p, srt_p, alpha0p, inv0p, wslf0p,
                                       off_n, srt_n, alpha0n, inv0n, wslf0n, b0p, b0n, xbufb, N);

  // layer 1: waves = 2 row-groups x 2 col-groups; single y-block -> A read once; bf16 C
  dim3 g1((N + 63) / 64, 1);
  k_mgemm<8, 1, 1, 128, 2, 2><<<g1, 256, 0, stream>>>(xbufb, w1f, h1b, (float*)nullptr, N,
                                                      asrc1p, adst1p, asrc1n, adst1n,
                                                      as1p, ad1p, as1n, ad1n);
  k_sa1<<<ngrid, 256, 0, stream>>>(as1p, ad1p, off_p, srt_p, alpha1p, inv1p, wslf1p,
                                   as1n, ad1n, off_n, srt_n, alpha1n, inv1n, wslf1n, N);
  k_gather1<<<ngrid, 256, 0, stream>>>(h1b, off_p, srt_p, alpha1p, inv1p, wslf1p,
                                       off_n, srt_n, alpha1n, inv1n, wslf1n, b1p, b1n, (float*)d_out, N);
}